// Round 6
// baseline (356.394 us; speedup 1.0000x reference)
//
#include <hip/hip_runtime.h>
#include <hip/hip_bf16.h>
#include <stdint.h>

#define DEV __device__ __forceinline__

typedef unsigned short ushort_t;
typedef __attribute__((ext_vector_type(8))) short bf16x8;  // 8 bf16 = 4 VGPRs
typedef __attribute__((ext_vector_type(4))) float f32x4;

// hardware packed f32->bf16 (RNE), 1 VALU inst (gfx950 v_cvt_pk_bf16_f32)
DEV uint32_t f2bf2(float lo, float hi) {
  uint32_t d;
  asm("v_cvt_pk_bf16_f32 %0, %1, %2" : "=v"(d) : "v"(lo), "v"(hi));
  return d;
}
DEV ushort_t f2bf(float f) { return (ushort_t)f2bf2(f, f); }

DEV void gload_lds16(const void* gp, void* lp) {
  __builtin_amdgcn_global_load_lds(
      (__attribute__((address_space(1))) void*)(void*)(uintptr_t)gp,
      (__attribute__((address_space(3))) void*)lp, 16, 0, 0);
}

// exact-GELU via branchless A&S 7.1.26 erf: |erf err| <= 1.5e-7 (invisible after
// bf16 rounding). ~15 VALU ops vs libm erff's ~30+ with branches.
DEV float gelu_fast(float x) {
  const float z = fabsf(x) * 0.70710678118654752f;
  const float t = __builtin_amdgcn_rcpf(fmaf(0.3275911f, z, 1.0f));
  float p = fmaf(1.061405429f, t, -1.453152027f);
  p = fmaf(p, t, 1.421413741f);
  p = fmaf(p, t, -0.284496736f);
  p = fmaf(p, t, 0.254829592f);
  p *= t;
  const float e = __builtin_amdgcn_exp2f(z * z * -1.4426950408889634f);  // e^{-z^2}
  const float er = fmaf(-p, e, 1.0f);                                    // erf(|x|/√2)
  const float s = copysignf(er, x);
  return 0.5f * x * (1.0f + s);
}

// ---------------- fused weight cvt + input LayerNorms (1 launch) ----------------
DEV void ln_row(const float* __restrict__ x, const float* __restrict__ g,
                const float* __restrict__ be, ushort_t* __restrict__ out, int row) {
  const int t = threadIdx.x;
  const float4 v = ((const float4*)(x + (size_t)row * 1024))[t];
  float s = v.x + v.y + v.z + v.w;
  float sq = v.x * v.x + v.y * v.y + v.z * v.z + v.w * v.w;
#pragma unroll
  for (int d = 1; d < 64; d <<= 1) { s += __shfl_xor(s, d); sq += __shfl_xor(sq, d); }
  __shared__ float sm[8];
  const int w = t >> 6, lane = t & 63;
  if (lane == 0) { sm[w * 2] = s; sm[w * 2 + 1] = sq; }
  __syncthreads();
  s = sm[0] + sm[2] + sm[4] + sm[6];
  sq = sm[1] + sm[3] + sm[5] + sm[7];
  const float mean = s * (1.f / 1024.f);
  const float var = sq * (1.f / 1024.f) - mean * mean;
  const float rstd = rsqrtf(var + 1e-5f);
  const float4 gv = ((const float4*)g)[t];
  const float4 bv = ((const float4*)be)[t];
  uint2 o;
  o.x = f2bf2((v.x - mean) * rstd * gv.x + bv.x, (v.y - mean) * rstd * gv.y + bv.y);
  o.y = f2bf2((v.z - mean) * rstd * gv.z + bv.z, (v.w - mean) * rstd * gv.w + bv.w);
  ((uint2*)(out + (size_t)row * 1024))[t] = o;
}

__global__ __launch_bounds__(256) void cvt_ln(
    const float* __restrict__ Wq, const float* __restrict__ Wk,
    const float* __restrict__ Wv, const float* __restrict__ Wo,
    const float* __restrict__ W1, const float* __restrict__ W2,
    ushort_t* __restrict__ WQKVB, ushort_t* __restrict__ WoB,
    ushort_t* __restrict__ W1B, ushort_t* __restrict__ W2B,
    const float* __restrict__ x_q, const float* __restrict__ x_kv,
    const float* __restrict__ qg, const float* __restrict__ qb,
    const float* __restrict__ kg, const float* __restrict__ kb,
    ushort_t* __restrict__ oq, ushort_t* __restrict__ okv) {
  if (blockIdx.x < 12288) {
    int i = blockIdx.x * 256 + threadIdx.x;  // float4 index over concatenated weights
    const float* src; ushort_t* dst; int j;
    if (i < 262144)            { src = Wq; dst = WQKVB;            j = i; }
    else if (i < 524288)       { src = Wk; dst = WQKVB + 1048576;  j = i - 262144; }
    else if (i < 786432)       { src = Wv; dst = WQKVB + 2097152;  j = i - 524288; }
    else if (i < 1048576)      { src = Wo; dst = WoB;              j = i - 786432; }
    else if (i < 2097152)      { src = W1; dst = W1B;              j = i - 1048576; }
    else                       { src = W2; dst = W2B;              j = i - 2097152; }
    float4 v = ((const float4*)src)[j];
    uint2 o; o.x = f2bf2(v.x, v.y); o.y = f2bf2(v.z, v.w);
    ((uint2*)dst)[j] = o;
  } else {
    const int r = blockIdx.x - 12288;
    if (r < 4096) ln_row(x_q, qg, qb, oq, r);
    else ln_row(x_kv, kg, kb, okv, r - 4096);
  }
}

__global__ __launch_bounds__(256) void ln_bf16(const float* __restrict__ x,
                                               const float* __restrict__ g,
                                               const float* __restrict__ be,
                                               ushort_t* __restrict__ out) {
  ln_row(x, g, be, out, blockIdx.x);
}

// XCD swizzle: cyclic wg->XCD dispatch means lin%8 = XCD. Remap so each XCD's
// resident blocks share gy/8 consecutive M-row tiles (A-tile / KV L2 locality).
DEV void xcd_remap(int gx, int gy, int& bx, int& by) {
  const int lin = by * gx + bx;
  const int xcd = lin & 7, s = lin >> 3;
  by = xcd * (gy >> 3) + s / gx;
  bx = s % gx;
}

enum { EPI_BF16 = 0, EPI_KV = 1, EPI_RESID = 2, EPI_GELU = 3, EPI_QKV = 4 };

// ---------------- GEMM (verified R2 structure): out[m,n] = sum_k A[m,k]*W[n,k] ----------
template <int BM, int TN, int BK, int EPI>
__global__ __launch_bounds__(256, (BM == 64) ? 4 : 3) void gemm_bt(
    const ushort_t* __restrict__ A,    // [M][K] bf16
    const ushort_t* __restrict__ A2,   // EPI_QKV: A for n0>=1024 (LNKV)
    const ushort_t* __restrict__ Wb,   // [N][K] bf16
    const float* __restrict__ bias, const float* __restrict__ bias2,
    const float* __restrict__ bias3,
    const float* __restrict__ resid,   // [M][N] f32 or null
    void* __restrict__ outp, void* __restrict__ outp2, void* __restrict__ outp3,
    int M, int N, int K, float oscale) {
  constexpr int WAVES_N = (TN == 128 || BM == 64) ? 2 : 1;
  constexpr int WAVES_M = 4 / WAVES_N;
  constexpr int NI = BM / WAVES_M / 16;  // M-frags per wave
  constexpr int NJ = TN / WAVES_N / 16;  // N-frags per wave
  constexpr int CH = BK / 8;             // 16B chunks per row
  constexpr int NA = (BM * CH) / 256;    // A staging loads per thread
  constexpr int NBL = (TN * CH) / 256;   // B staging loads per thread
  constexpr int KS = BK / 32;            // mfma K-steps per tile
  __shared__ ushort_t As[2][BM * BK];
  __shared__ ushort_t Bs[2][TN * BK];
  const int t = threadIdx.x;
  const int w = t >> 6, lane = t & 63;
  const int qd = lane >> 4, ql = lane & 15;
  int bx = blockIdx.x, by = blockIdx.y;
  xcd_remap(gridDim.x, gridDim.y, bx, by);
  const int m0 = by * BM, n0 = bx * TN;
  const int wm = (w / WAVES_N) * (BM / WAVES_M);
  const int wn = (w % WAVES_N) * (TN / WAVES_N);
  const int sw = (BK == 64) ? (ql & 7) : ((ql >> 1) & 3);  // read-side swizzle key

  const ushort_t* Ause = (EPI == EPI_QKV && n0 >= 1024) ? A2 : A;

  // hoisted staging pointers (advance by BK elems per iter); source chunk swizzled
  const ushort_t* pa[NA];
#pragma unroll
  for (int p = 0; p < NA; p++) {
    int n = p * 256 + t, row = n / CH, c = n % CH;
    int g = (BK == 64) ? (c ^ (row & 7)) : (c ^ ((row >> 1) & 3));
    pa[p] = Ause + (size_t)(m0 + row) * K + g * 8;
  }
  const ushort_t* pb[NBL];
#pragma unroll
  for (int p = 0; p < NBL; p++) {
    int n = p * 256 + t, row = n / CH, c = n % CH;
    int g = (BK == 64) ? (c ^ (row & 7)) : (c ^ ((row >> 1) & 3));
    pb[p] = Wb + (size_t)(n0 + row) * K + g * 8;
  }

  // preload tile 0
#pragma unroll
  for (int p = 0; p < NA; p++) { gload_lds16(pa[p], &As[0][(p * 256 + t) * 8]); pa[p] += BK; }
#pragma unroll
  for (int p = 0; p < NBL; p++) { gload_lds16(pb[p], &Bs[0][(p * 256 + t) * 8]); pb[p] += BK; }
  __syncthreads();

  f32x4 acc[NI][NJ] = {};
  const int NIT = K / BK;
  int cur = 0;

  for (int it = 0; it < NIT; ++it) {
    if (it + 1 < NIT) {  // prefetch next tile into the other buffer
#pragma unroll
      for (int p = 0; p < NA; p++) { gload_lds16(pa[p], &As[1 ^ cur][(p * 256 + t) * 8]); pa[p] += BK; }
#pragma unroll
      for (int p = 0; p < NBL; p++) { gload_lds16(pb[p], &Bs[1 ^ cur][(p * 256 + t) * 8]); pb[p] += BK; }
    }
    const ushort_t* Ac = As[cur];
    const ushort_t* Bc = Bs[cur];
#pragma unroll
    for (int ks = 0; ks < KS; ks++) {
      bf16x8 af[NI], bf[NJ];
#pragma unroll
      for (int i = 0; i < NI; i++)
        af[i] = *(const bf16x8*)&Ac[(wm + i * 16 + ql) * BK + ((ks * 4 + qd) ^ sw) * 8];
#pragma unroll
      for (int j = 0; j < NJ; j++)
        bf[j] = *(const bf16x8*)&Bc[(wn + j * 16 + ql) * BK + ((ks * 4 + qd) ^ sw) * 8];
#pragma unroll
      for (int i = 0; i < NI; i++)
#pragma unroll
        for (int j = 0; j < NJ; j++)
          acc[i][j] = __builtin_amdgcn_mfma_f32_16x16x32_bf16(af[i], bf[j], acc[i][j], 0, 0, 0);
    }
    __syncthreads();  // readers of cur done + prefetch drained
    cur ^= 1;
  }

#pragma unroll
  for (int i = 0; i < NI; i++) {
    const int mr = m0 + wm + i * 16 + qd * 4;
#pragma unroll
    for (int j = 0; j < NJ; j++) {
      const int col = n0 + wn + j * 16 + ql;
      f32x4 v = acc[i][j];
      if constexpr (EPI == EPI_BF16) {
        const float bb = bias[col];
        ushort_t* o = (ushort_t*)outp;
#pragma unroll
        for (int r = 0; r < 4; r++) o[(size_t)(mr + r) * N + col] = f2bf((v[r] + bb) * oscale);
      } else if constexpr (EPI == EPI_QKV) {
        if (col < 1024) {  // Q half (pre-scaled by oscale for exp2 softmax)
          const float bb = bias[col];
          ushort_t* o = (ushort_t*)outp;
#pragma unroll
          for (int r = 0; r < 4; r++) o[(size_t)(mr + r) * 1024 + col] = f2bf((v[r] + bb) * oscale);
        } else if (col < 2048) {  // K -> [4096][1024] bf16
          const int c2 = col - 1024;
          const float bb = bias2[c2];
          ushort_t* o = (ushort_t*)outp2;
#pragma unroll
          for (int r = 0; r < 4; r++) o[(size_t)(mr + r) * 1024 + c2] = f2bf(v[r] + bb);
        } else {  // V -> V^T [B=2][H=16][HD=64][L=2048] bf16
          const int vc = col - 2048;
          const float bb = bias3[vc];
          const int h = vc >> 6, d = vc & 63;
          const int b = mr >> 11, l0 = mr & 2047;
          uint2 pk;
          pk.x = f2bf2(v[0] + bb, v[1] + bb);
          pk.y = f2bf2(v[2] + bb, v[3] + bb);
          *(uint2*)((ushort_t*)outp3 + ((((size_t)b * 16 + h) * 64 + d) * 2048 + l0)) = pk;
        }
      } else if constexpr (EPI == EPI_RESID) {
        const float bb = bias[col];
        float* o = (float*)outp;
#pragma unroll
        for (int r = 0; r < 4; r++) {
          size_t idx = (size_t)(mr + r) * N + col;
          o[idx] = resid[idx] + v[r] + bb;
        }
      } else if constexpr (EPI == EPI_GELU) {  // exact GELU, branchless fast erf
        const float bb = bias[col];
        ushort_t* o = (ushort_t*)outp;
#pragma unroll
        for (int r = 0; r < 4; r++)
          o[(size_t)(mr + r) * N + col] = f2bf(gelu_fast(v[r] + bb));
      }
    }
  }
}

// ---------------- 256x256 one-drain-per-tile GEMM (v2), BK=64, 8 waves, 128 KB LDS ----
// 8 waves as 2(M) x 4(N); per-wave out 128x64, acc[8][4]. Per K-tile: 4 phases =
// (ks, N-half); af[8] (A frags for ks) read ONCE per ks and HELD across both N-half
// phases -> 24 ds_read_b128/wave/tile (vs 48 for quadrant phasing), 16 MFMA/phase.
// Staging: ALL 8 gload_lds of tile T+1 issued at phase 0 of tile T; single
// s_waitcnt vmcnt(0) at tile end (amortized over 64 MFMA/wave, ~3.5 phases of
// latency cover; A/B panels are L2-resident at these sizes).
// Correctness: only the tile-boundary barrier needs fences (buffer swap):
//  - reads of buf[cur] complete before it (lgkm forced by MFMA data-deps),
//  - each wave's gloads into buf[cur^1] drained by its own vmcnt(0) before it,
//  - sched_barrier(0) fences stop the compiler moving LDS ops across the swap.
// Mid-phase raw s_barriers (no fences) keep waves loosely aligned; any compiler
// motion across them stays within the tile where all of buf[cur] is valid.
template <int EPI>
__global__ __launch_bounds__(512, 2) void gemm256v2(
    const ushort_t* __restrict__ A, const ushort_t* __restrict__ Wb,
    const float* __restrict__ bias,
    void* __restrict__ outp, int M, int N, int K, float oscale) {
  __shared__ ushort_t As[2][256 * 64];
  __shared__ ushort_t Bs[2][256 * 64];
  const int t = threadIdx.x;
  const int w = t >> 6, lane = t & 63;
  const int qd = lane >> 4, ql = lane & 15;
  const int wr = w >> 2, wc = w & 3;  // 2(M) x 4(N) wave grid
  int bx = blockIdx.x, by = blockIdx.y;
  xcd_remap(gridDim.x, gridDim.y, bx, by);
  const int m0 = by * 256, n0 = bx * 256;
  const int sw = ql & 7;

  // staging pointers: gload p covers LDS rows [p*64, p*64+64) (512 thr x 16B = 64 rows)
  const ushort_t* pa[4];
  const ushort_t* pb[4];
#pragma unroll
  for (int p = 0; p < 4; p++) {
    const int n = p * 512 + t, row = n >> 3, c = (n & 7) ^ (row & 7);
    pa[p] = A + (size_t)(m0 + row) * K + c * 8;
    pb[p] = Wb + (size_t)(n0 + row) * K + c * 8;
  }

  // prologue: tile 0
#pragma unroll
  for (int p = 0; p < 4; p++) { gload_lds16(pa[p], &As[0][(p * 512 + t) * 8]); pa[p] += 64; }
#pragma unroll
  for (int p = 0; p < 4; p++) { gload_lds16(pb[p], &Bs[0][(p * 512 + t) * 8]); pb[p] += 64; }
  __syncthreads();

  f32x4 acc[8][4] = {};
  const int NT = K / 64;
  int cur = 0;

#define AFREAD(KS)                                                              \
  _Pragma("unroll") for (int i = 0; i < 8; i++)                                 \
      af[i] = *(const bf16x8*)&Ac[(wr * 128 + i * 16 + ql) * 64 +               \
                                  (((KS) * 4 + qd) ^ sw) * 8];
#define BFREAD(KS, NH)                                                          \
  _Pragma("unroll") for (int jj = 0; jj < 2; jj++)                              \
      bf[jj] = *(const bf16x8*)&Bc[(wc * 64 + (NH) * 32 + jj * 16 + ql) * 64 +  \
                                   (((KS) * 4 + qd) ^ sw) * 8];
#define MM(NH)                                                                  \
  __builtin_amdgcn_s_setprio(1);                                                \
  _Pragma("unroll") for (int i = 0; i < 8; i++)                                 \
      _Pragma("unroll") for (int jj = 0; jj < 2; jj++)                          \
          acc[i][(NH) * 2 + jj] = __builtin_amdgcn_mfma_f32_16x16x32_bf16(      \
              af[i], bf[jj], acc[i][(NH) * 2 + jj], 0, 0, 0);                   \
  __builtin_amdgcn_s_setprio(0);

  for (int T = 0; T < NT; ++T) {
    const ushort_t* Ac = As[cur];
    const ushort_t* Bc = Bs[cur];
    ushort_t* An = As[cur ^ 1];
    ushort_t* Bn = Bs[cur ^ 1];
    const bool st = (T + 1 < NT);
    bf16x8 af[8], bf[2];

    // phase 0 (ks0, nh0): stage ALL of tile T+1, read af(ks0)+bf, 16 MFMA
    if (st) {
#pragma unroll
      for (int p = 0; p < 4; p++) { gload_lds16(pa[p], &An[(p * 512 + t) * 8]); pa[p] += 64; }
#pragma unroll
      for (int p = 0; p < 4; p++) { gload_lds16(pb[p], &Bn[(p * 512 + t) * 8]); pb[p] += 64; }
    }
    AFREAD(0)
    BFREAD(0, 0)
    MM(0)
    __builtin_amdgcn_s_barrier();

    // phase 1 (ks0, nh1): af held
    BFREAD(0, 1)
    MM(1)
    __builtin_amdgcn_s_barrier();

    // phase 2 (ks1, nh0)
    AFREAD(1)
    BFREAD(1, 0)
    MM(0)
    __builtin_amdgcn_s_barrier();

    // phase 3 (ks1, nh1): tile-end drain + fenced barrier (buffer swap)
    BFREAD(1, 1)
    MM(1)
    if (st) asm volatile("s_waitcnt vmcnt(0)" ::: "memory");
    __builtin_amdgcn_sched_barrier(0);
    __builtin_amdgcn_s_barrier();
    __builtin_amdgcn_sched_barrier(0);
    cur ^= 1;
  }
#undef AFREAD
#undef BFREAD
#undef MM

#pragma unroll
  for (int i = 0; i < 8; i++) {
    const int mr = m0 + wr * 128 + i * 16 + qd * 4;
#pragma unroll
    for (int j = 0; j < 4; j++) {
      const int col = n0 + wc * 64 + j * 16 + ql;
      f32x4 v = acc[i][j];
      if constexpr (EPI == EPI_GELU) {
        const float bb = bias[col];
        ushort_t* o = (ushort_t*)outp;
#pragma unroll
        for (int r = 0; r < 4; r++)
          o[(size_t)(mr + r) * N + col] = f2bf(gelu_fast(v[r] + bb));
      } else if constexpr (EPI == EPI_BF16) {
        const float bb = bias[col];
        ushort_t* o = (ushort_t*)outp;
#pragma unroll
        for (int r = 0; r < 4; r++)
          o[(size_t)(mr + r) * N + col] = f2bf((v[r] + bb) * oscale);
      }
    }
  }
}

// ---------------- flash attention with softmax-1, fixed m=0, S^T orientation ------
__global__ __launch_bounds__(256, 2) void flash_attn(const ushort_t* __restrict__ Qg,
                                                     const ushort_t* __restrict__ Kg,
                                                     const ushort_t* __restrict__ VTg,
                                                     ushort_t* __restrict__ Og) {
  __shared__ ushort_t QPs[128 * 64];    // 16 KB: Q tile, then P[n][l] (Q dead after hoist)
  __shared__ ushort_t Ks[2][64 * 64];   // 16 KB (dbuf K tile [l][d])
  __shared__ ushort_t Vs[2][64 * 64];   // 16 KB (dbuf V^T tile [d][l])
  const int t = threadIdx.x, w = t >> 6, lane = t & 63;
  const int qd = lane >> 4, ql = lane & 15;
  int bx = blockIdx.x, bh = blockIdx.y;
  xcd_remap(gridDim.x, gridDim.y, bx, bh);
  const int b = bh >> 4, h = bh & 15;
  const int n0 = bx * 128;
  const ushort_t* Qp = Qg + ((size_t)b * 2048 + n0) * 1024 + h * 64;
  const ushort_t* Kp = Kg + (size_t)b * 2048 * 1024 + h * 64;
  const ushort_t* Vp = VTg + (size_t)bh * 64 * 2048;
  const int sw = ql & 7;  // read-side swizzle key

  // hoisted staging pointers: K advances 64 rows, V 64 cols per tile
  const ushort_t* kp2[2];
  const ushort_t* vp2[2];
#pragma unroll
  for (int p = 0; p < 2; p++) {
    int n = p * 256 + t, row = n >> 3, c = (n & 7) ^ (row & 7);
    kp2[p] = Kp + (size_t)row * 1024 + c * 8;
    vp2[p] = Vp + (size_t)row * 2048 + c * 8;
  }

  // stage Q (swizzled) + K/V tile 0
#pragma unroll
  for (int p = 0; p < 4; p++) {
    int n = p * 256 + t, row = n >> 3, c = (n & 7) ^ (row & 7);
    gload_lds16(Qp + (size_t)row * 1024 + c * 8, &QPs[n * 8]);
  }
#pragma unroll
  for (int p = 0; p < 2; p++) {
    int n = p * 256 + t;
    gload_lds16(kp2[p], &Ks[0][n * 8]);
    gload_lds16(vp2[p], &Vs[0][n * 8]);
    kp2[p] += 64 * 1024;
    vp2[p] += 64;
  }
  __syncthreads();

  // hoist Q fragments (loop-invariant); Qs LDS dead afterwards
  bf16x8 aq[2][2];
#pragma unroll
  for (int i = 0; i < 2; i++)
#pragma unroll
    for (int ks = 0; ks < 2; ks++)
      aq[i][ks] = *(const bf16x8*)&QPs[(w * 32 + i * 16 + ql) * 64 + ((ks * 4 + qd) ^ sw) * 8];
  __syncthreads();  // all aq reads done before any wave writes P into QPs

  f32x4 accO[2][4] = {};
  float lro2[2] = {0.f, 0.f};  // denom partials for n = w*32 + i*16 + ql (quad-partial)

  int cur = 0;
  for (int lt = 0; lt < 32; ++lt) {
    if (lt + 1 < 32) {
#pragma unroll
      for (int p = 0; p < 2; p++) {
        int n = p * 256 + t;
        gload_lds16(kp2[p], &Ks[1 ^ cur][n * 8]);
        gload_lds16(vp2[p], &Vs[1 ^ cur][n * 8]);
        kp2[p] += 64 * 1024;
        vp2[p] += 64;
      }
    }
    const ushort_t* Kc = Ks[cur];
    const ushort_t* Vc = Vs[cur];

    // S^T = K (Q*0.1803)^T : accS[j][i], rows l = j*16+qd*4+r, cols n = i*16+ql
    f32x4 accS[4][2] = {};
#pragma unroll
    for (int ks = 0; ks < 2; ks++) {
      bf16x8 bk[4];
#pragma unroll
      for (int j = 0; j < 4; j++)
        bk[j] = *(const bf16x8*)&Kc[(j * 16 + ql) * 64 + ((ks * 4 + qd) ^ sw) * 8];
      __builtin_amdgcn_s_setprio(1);
#pragma unroll
      for (int j = 0; j < 4; j++)
#pragma unroll
        for (int i = 0; i < 2; i++)
          accS[j][i] = __builtin_amdgcn_mfma_f32_16x16x32_bf16(bk[j], aq[i][ks], accS[j][i], 0, 0, 0);
      __builtin_amdgcn_s_setprio(0);
    }

    // p = exp2(s_hat); denom += p; pack 4 consecutive l -> one b64 P-write
#pragma unroll
    for (int j = 0; j < 4; j++)
#pragma unroll
      for (int i = 0; i < 2; i++) {
        f32x4 p;
#pragma unroll
        for (int r = 0; r < 4; r++) {
          p[r] = __builtin_amdgcn_exp2f(accS[j][i][r]);
          lro2[i] += p[r];
        }
        const int n = w * 32 + i * 16 + ql;
        // l = j*16 + qd*4 + r; 16B chunk c = j*2 + (qd>>1), swizzled c^(n&7)=c^sw
        const int coff = (((j * 2 + (qd >> 1)) ^ sw) << 3) + ((qd & 1) << 2);
        uint2 pk; pk.x = f2bf2(p[0], p[1]); pk.y = f2bf2(p[2], p[3]);
        *(uint2*)&QPs[n * 64 + coff] = pk;
      }

    // O += P V (P rows intra-wave; V^T B-frags from Vs)
#pragma unroll
    for (int ks = 0; ks < 2; ks++) {
      bf16x8 ap[2], bv[4];
#pragma unroll
      for (int i = 0; i < 2; i++)
        ap[i] = *(const bf16x8*)&QPs[(w * 32 + i * 16 + ql) * 64 + ((ks * 4 + qd) ^ sw) * 8];
#pragma unroll
      for (int jo = 0; jo < 4; jo++)
        bv[jo] = *(const bf16x8*)&Vc[(jo * 16 + ql) * 64 + ((ks * 4 + qd) ^ sw) * 8];
      __builtin_amdgcn_s_setprio(1);
#pragma unroll
      for (int i = 0; i < 2; i++)
#pragma unroll
        for (int jo = 0; jo < 4; jo++)
          accO[i][jo] = __builtin_amdgcn_mfma_f32_16x16x32_bf16(ap[i], bv[jo], accO[i][jo], 0, 0, 0);
      __builtin_amdgcn_s_setprio(0);
    }

    __syncthreads();  // K/V[cur] readers done + next-tile loads drained
    cur ^= 1;
  }

  // finish denominators: sum across quads (each quad held disjoint l ranges)
  float dn[2];
#pragma unroll
  for (int i = 0; i < 2; i++) {
    float l = lro2[i];
    l += __shfl_xor(l, 16);
    l += __shfl_xor(l, 32);
    dn[i] = l + 1.0f;  // +1: implicit zero logit of softmax-1
  }

#pragma unroll
  for (int i = 0; i < 2; i++)
#pragma unroll
    for (int r = 0; r < 4; r++) {
      // denom for row n' = qd*4+r lives in lane ql = n' (quad-uniform after reduce)
      const float inv = 1.0f / __shfl(dn[i], qd * 4 + r);
      const int row = n0 + w * 32 + i * 16 + qd * 4 + r;
#pragma unroll
      for (int jo = 0; jo < 4; jo++)
        Og[((size_t)b * 2048 + row) * 1024 + h * 64 + jo * 16 + ql] =
            f2bf(accO[i][jo][r] * inv);
    }
}

// ---------------- launch ----------------
extern "C" void kernel_launch(void* const* d_in, const int* in_sizes, int n_in,
                              void* d_out, int out_size, void* d_ws, size_t ws_size,
                              hipStream_t stream) {
  const float* x_q = (const float*)d_in[0];
  const float* x_kv = (const float*)d_in[1];
  const float* qn_g = (const float*)d_in[2];
  const float* qn_b = (const float*)d_in[3];
  const float* kvn_g = (const float*)d_in[4];
  const float* kvn_b = (const float*)d_in[5];
  const float* Wq = (const float*)d_in[6];
  const float* bq = (const float*)d_in[7];
  const float* Wk = (const float*)d_in[8];
  const float* bk = (const float*)d_in[9];
  const float* Wv = (const float*)d_in[10];
  const float* bv = (const float*)d_in[11];
  const float* Wo = (const float*)d_in[12];
  const float* bo = (const float*)d_in[13];
  const float* n2_g = (const float*)d_in[14];
  const float* n2_b = (const float*)d_in[15];
  const float* W1 = (const float*)d_in[16];
  const float* b1 = (const float*)d_in[17];
  const float* W2 = (const float*)d_in[18];
  const float* b2 = (const float*)d_in[19];

  char* ws = (char*)d_ws;
  const size_t MB = 1ull << 20;
  ushort_t* WQKVB = (ushort_t*)(ws + 0 * MB);  // 6 MB ([Wq;Wk;Wv], 3072x1024)
  ushort_t* WoB = (ushort_t*)(ws + 6 * MB);    // 2 MB
  ushort_t* W1B = (ushort_t*)(ws + 8 * MB);    // 8 MB
  ushort_t* W2B = (ushort_t*)(ws + 16 * MB);   // 8 MB
  ushort_t* LNQ = (ushort_t*)(ws + 24 * MB);
  ushort_t* LNKV = (ushort_t*)(ws + 32 * MB);
  ushort_t* Qb = (ushort_t*)(ws + 40 * MB);
  ushort_t* Kb = (ushort_t*)(ws + 48 * MB);
  ushort_t* VTb = (ushort_t*)(ws + 56 * MB);
  ushort_t* AOb = (ushort_t*)(ws + 64 * MB);
  float* Xf = (float*)(ws + 72 * MB);          // 16 MB
  ushort_t* LN2 = (ushort_t*)(ws + 88 * MB);
  ushort_t* Hb = (ushort_t*)(ws + 24 * MB);    // 32 MB, overlays LNQ/LNKV/Qb/Kb (dead by MLP1)

  // fold softmax scale (1/8) and exp->exp2 (log2 e) into the Q projection
  const float QSCALE = 0.18033688011112042f;  // 0.125 * log2(e)

  // fused weight conversion + input LayerNorms (one launch, independent work)
  cvt_ln<<<20480, 256, 0, stream>>>(Wq, Wk, Wv, Wo, W1, W2, WQKVB, WoB, W1B, W2B,
                                    x_q, x_kv, qn_g, qn_b, kvn_g, kvn_b, LNQ, LNKV);

  // merged Q+K+V projection: N=3072, A = LNQ for n<1024 else LNKV (verified 128^2)
  gemm_bt<128, 128, 32, EPI_QKV><<<dim3(24, 32), 256, 0, stream>>>(
      LNQ, LNKV, WQKVB, bq, bk, bv, nullptr, Qb, Kb, VTb, 4096, 3072, 1024, QSCALE);

  flash_attn<<<dim3(16, 32), 256, 0, stream>>>(Qb, Kb, VTb, AOb);

  // out-proj: BM=64 tiles -> 1024 blocks (4/CU); verified 2-dbuf structure
  gemm_bt<64, 64, 64, EPI_RESID><<<dim3(16, 64), 256, 0, stream>>>(
      AOb, nullptr, WoB, bo, nullptr, nullptr, x_q, Xf, nullptr, nullptr,
      4096, 1024, 1024, 1.0f);
  ln_bf16<<<4096, 256, 0, stream>>>(Xf, n2_g, n2_b, LN2);
  // MLP up-proj + GELU: 256^2 one-drain-per-tile kernel (grid 16x16 = 1 block/CU)
  gemm256v2<EPI_GELU><<<dim3(16, 16), 512, 0, stream>>>(
      LN2, W1B, b1, Hb, 4096, 4096, 1024, 1.0f);
  gemm_bt<64, 64, 64, EPI_RESID><<<dim3(16, 64), 256, 0, stream>>>(
      Hb, nullptr, W2B, b2, nullptr, nullptr, Xf, (float*)d_out, nullptr, nullptr,
      4096, 1024, 4096, 1.0f);
}

// Round 7
// 355.941 us; speedup vs baseline: 1.0013x; 1.0013x over previous
//
#include <hip/hip_runtime.h>
#include <hip/hip_bf16.h>
#include <stdint.h>

#define DEV __device__ __forceinline__

typedef unsigned short ushort_t;
typedef __attribute__((ext_vector_type(8))) short bf16x8;  // 8 bf16 = 4 VGPRs
typedef __attribute__((ext_vector_type(4))) float f32x4;

// hardware packed f32->bf16 (RNE), 1 VALU inst (gfx950 v_cvt_pk_bf16_f32)
DEV uint32_t f2bf2(float lo, float hi) {
  uint32_t d;
  asm("v_cvt_pk_bf16_f32 %0, %1, %2" : "=v"(d) : "v"(lo), "v"(hi));
  return d;
}
DEV ushort_t f2bf(float f) { return (ushort_t)f2bf2(f, f); }

DEV void gload_lds16(const void* gp, void* lp) {
  __builtin_amdgcn_global_load_lds(
      (__attribute__((address_space(1))) void*)(void*)(uintptr_t)gp,
      (__attribute__((address_space(3))) void*)lp, 16, 0, 0);
}

// exact-GELU via branchless A&S 7.1.26 erf: |erf err| <= 1.5e-7 (invisible after
// bf16 rounding). ~15 VALU ops vs libm erff's ~30+ with branches.
DEV float gelu_fast(float x) {
  const float z = fabsf(x) * 0.70710678118654752f;
  const float t = __builtin_amdgcn_rcpf(fmaf(0.3275911f, z, 1.0f));
  float p = fmaf(1.061405429f, t, -1.453152027f);
  p = fmaf(p, t, 1.421413741f);
  p = fmaf(p, t, -0.284496736f);
  p = fmaf(p, t, 0.254829592f);
  p *= t;
  const float e = __builtin_amdgcn_exp2f(z * z * -1.4426950408889634f);  // e^{-z^2}
  const float er = fmaf(-p, e, 1.0f);                                    // erf(|x|/√2)
  const float s = copysignf(er, x);
  return 0.5f * x * (1.0f + s);
}

// ---------------- fused weight cvt + input LayerNorms (1 launch) ----------------
DEV void ln_row(const float* __restrict__ x, const float* __restrict__ g,
                const float* __restrict__ be, ushort_t* __restrict__ out, int row) {
  const int t = threadIdx.x;
  const float4 v = ((const float4*)(x + (size_t)row * 1024))[t];
  float s = v.x + v.y + v.z + v.w;
  float sq = v.x * v.x + v.y * v.y + v.z * v.z + v.w * v.w;
#pragma unroll
  for (int d = 1; d < 64; d <<= 1) { s += __shfl_xor(s, d); sq += __shfl_xor(sq, d); }
  __shared__ float sm[8];
  const int w = t >> 6, lane = t & 63;
  if (lane == 0) { sm[w * 2] = s; sm[w * 2 + 1] = sq; }
  __syncthreads();
  s = sm[0] + sm[2] + sm[4] + sm[6];
  sq = sm[1] + sm[3] + sm[5] + sm[7];
  const float mean = s * (1.f / 1024.f);
  const float var = sq * (1.f / 1024.f) - mean * mean;
  const float rstd = rsqrtf(var + 1e-5f);
  const float4 gv = ((const float4*)g)[t];
  const float4 bv = ((const float4*)be)[t];
  uint2 o;
  o.x = f2bf2((v.x - mean) * rstd * gv.x + bv.x, (v.y - mean) * rstd * gv.y + bv.y);
  o.y = f2bf2((v.z - mean) * rstd * gv.z + bv.z, (v.w - mean) * rstd * gv.w + bv.w);
  ((uint2*)(out + (size_t)row * 1024))[t] = o;
}

__global__ __launch_bounds__(256) void cvt_ln(
    const float* __restrict__ Wq, const float* __restrict__ Wk,
    const float* __restrict__ Wv, const float* __restrict__ Wo,
    const float* __restrict__ W1, const float* __restrict__ W2,
    ushort_t* __restrict__ WQKVB, ushort_t* __restrict__ WoB,
    ushort_t* __restrict__ W1B, ushort_t* __restrict__ W2B,
    const float* __restrict__ x_q, const float* __restrict__ x_kv,
    const float* __restrict__ qg, const float* __restrict__ qb,
    const float* __restrict__ kg, const float* __restrict__ kb,
    ushort_t* __restrict__ oq, ushort_t* __restrict__ okv) {
  if (blockIdx.x < 12288) {
    int i = blockIdx.x * 256 + threadIdx.x;  // float4 index over concatenated weights
    const float* src; ushort_t* dst; int j;
    if (i < 262144)            { src = Wq; dst = WQKVB;            j = i; }
    else if (i < 524288)       { src = Wk; dst = WQKVB + 1048576;  j = i - 262144; }
    else if (i < 786432)       { src = Wv; dst = WQKVB + 2097152;  j = i - 524288; }
    else if (i < 1048576)      { src = Wo; dst = WoB;              j = i - 786432; }
    else if (i < 2097152)      { src = W1; dst = W1B;              j = i - 1048576; }
    else                       { src = W2; dst = W2B;              j = i - 2097152; }
    float4 v = ((const float4*)src)[j];
    uint2 o; o.x = f2bf2(v.x, v.y); o.y = f2bf2(v.z, v.w);
    ((uint2*)dst)[j] = o;
  } else {
    const int r = blockIdx.x - 12288;
    if (r < 4096) ln_row(x_q, qg, qb, oq, r);
    else ln_row(x_kv, kg, kb, okv, r - 4096);
  }
}

__global__ __launch_bounds__(256) void ln_bf16(const float* __restrict__ x,
                                               const float* __restrict__ g,
                                               const float* __restrict__ be,
                                               ushort_t* __restrict__ out) {
  ln_row(x, g, be, out, blockIdx.x);
}

// XCD swizzle: cyclic wg->XCD dispatch means lin%8 = XCD. Remap so each XCD's
// resident blocks share gy/8 consecutive M-row tiles (A-tile / KV L2 locality).
DEV void xcd_remap(int gx, int gy, int& bx, int& by) {
  const int lin = by * gx + bx;
  const int xcd = lin & 7, s = lin >> 3;
  by = xcd * (gy >> 3) + s / gx;
  bx = s % gx;
}

enum { EPI_BF16 = 0, EPI_KV = 1, EPI_RESID = 2, EPI_GELU = 3, EPI_QKV = 4 };

// ---------------- GEMM (verified R2 structure): out[m,n] = sum_k A[m,k]*W[n,k] ----------
template <int BM, int TN, int BK, int EPI>
__global__ __launch_bounds__(256, (BM == 64) ? 4 : 3) void gemm_bt(
    const ushort_t* __restrict__ A,    // [M][K] bf16
    const ushort_t* __restrict__ A2,   // EPI_QKV: A for n0>=1024 (LNKV)
    const ushort_t* __restrict__ Wb,   // [N][K] bf16
    const float* __restrict__ bias, const float* __restrict__ bias2,
    const float* __restrict__ bias3,
    const float* __restrict__ resid,   // [M][N] f32 or null
    void* __restrict__ outp, void* __restrict__ outp2, void* __restrict__ outp3,
    int M, int N, int K, float oscale) {
  constexpr int WAVES_N = (TN == 128 || BM == 64) ? 2 : 1;
  constexpr int WAVES_M = 4 / WAVES_N;
  constexpr int NI = BM / WAVES_M / 16;  // M-frags per wave
  constexpr int NJ = TN / WAVES_N / 16;  // N-frags per wave
  constexpr int CH = BK / 8;             // 16B chunks per row
  constexpr int NA = (BM * CH) / 256;    // A staging loads per thread
  constexpr int NBL = (TN * CH) / 256;   // B staging loads per thread
  constexpr int KS = BK / 32;            // mfma K-steps per tile
  __shared__ ushort_t As[2][BM * BK];
  __shared__ ushort_t Bs[2][TN * BK];
  const int t = threadIdx.x;
  const int w = t >> 6, lane = t & 63;
  const int qd = lane >> 4, ql = lane & 15;
  int bx = blockIdx.x, by = blockIdx.y;
  xcd_remap(gridDim.x, gridDim.y, bx, by);
  const int m0 = by * BM, n0 = bx * TN;
  const int wm = (w / WAVES_N) * (BM / WAVES_M);
  const int wn = (w % WAVES_N) * (TN / WAVES_N);
  const int sw = (BK == 64) ? (ql & 7) : ((ql >> 1) & 3);  // read-side swizzle key

  const ushort_t* Ause = (EPI == EPI_QKV && n0 >= 1024) ? A2 : A;

  // hoisted staging pointers (advance by BK elems per iter); source chunk swizzled
  const ushort_t* pa[NA];
#pragma unroll
  for (int p = 0; p < NA; p++) {
    int n = p * 256 + t, row = n / CH, c = n % CH;
    int g = (BK == 64) ? (c ^ (row & 7)) : (c ^ ((row >> 1) & 3));
    pa[p] = Ause + (size_t)(m0 + row) * K + g * 8;
  }
  const ushort_t* pb[NBL];
#pragma unroll
  for (int p = 0; p < NBL; p++) {
    int n = p * 256 + t, row = n / CH, c = n % CH;
    int g = (BK == 64) ? (c ^ (row & 7)) : (c ^ ((row >> 1) & 3));
    pb[p] = Wb + (size_t)(n0 + row) * K + g * 8;
  }

  // preload tile 0
#pragma unroll
  for (int p = 0; p < NA; p++) { gload_lds16(pa[p], &As[0][(p * 256 + t) * 8]); pa[p] += BK; }
#pragma unroll
  for (int p = 0; p < NBL; p++) { gload_lds16(pb[p], &Bs[0][(p * 256 + t) * 8]); pb[p] += BK; }
  __syncthreads();

  f32x4 acc[NI][NJ] = {};
  const int NIT = K / BK;
  int cur = 0;

  for (int it = 0; it < NIT; ++it) {
    if (it + 1 < NIT) {  // prefetch next tile into the other buffer
#pragma unroll
      for (int p = 0; p < NA; p++) { gload_lds16(pa[p], &As[1 ^ cur][(p * 256 + t) * 8]); pa[p] += BK; }
#pragma unroll
      for (int p = 0; p < NBL; p++) { gload_lds16(pb[p], &Bs[1 ^ cur][(p * 256 + t) * 8]); pb[p] += BK; }
    }
    const ushort_t* Ac = As[cur];
    const ushort_t* Bc = Bs[cur];
#pragma unroll
    for (int ks = 0; ks < KS; ks++) {
      bf16x8 af[NI], bf[NJ];
#pragma unroll
      for (int i = 0; i < NI; i++)
        af[i] = *(const bf16x8*)&Ac[(wm + i * 16 + ql) * BK + ((ks * 4 + qd) ^ sw) * 8];
#pragma unroll
      for (int j = 0; j < NJ; j++)
        bf[j] = *(const bf16x8*)&Bc[(wn + j * 16 + ql) * BK + ((ks * 4 + qd) ^ sw) * 8];
#pragma unroll
      for (int i = 0; i < NI; i++)
#pragma unroll
        for (int j = 0; j < NJ; j++)
          acc[i][j] = __builtin_amdgcn_mfma_f32_16x16x32_bf16(af[i], bf[j], acc[i][j], 0, 0, 0);
    }
    __syncthreads();  // readers of cur done + prefetch drained
    cur ^= 1;
  }

#pragma unroll
  for (int i = 0; i < NI; i++) {
    const int mr = m0 + wm + i * 16 + qd * 4;
#pragma unroll
    for (int j = 0; j < NJ; j++) {
      const int col = n0 + wn + j * 16 + ql;
      f32x4 v = acc[i][j];
      if constexpr (EPI == EPI_BF16) {
        const float bb = bias[col];
        ushort_t* o = (ushort_t*)outp;
#pragma unroll
        for (int r = 0; r < 4; r++) o[(size_t)(mr + r) * N + col] = f2bf((v[r] + bb) * oscale);
      } else if constexpr (EPI == EPI_QKV) {
        if (col < 1024) {  // Q half (pre-scaled by oscale for exp2 softmax)
          const float bb = bias[col];
          ushort_t* o = (ushort_t*)outp;
#pragma unroll
          for (int r = 0; r < 4; r++) o[(size_t)(mr + r) * 1024 + col] = f2bf((v[r] + bb) * oscale);
        } else if (col < 2048) {  // K -> [4096][1024] bf16
          const int c2 = col - 1024;
          const float bb = bias2[c2];
          ushort_t* o = (ushort_t*)outp2;
#pragma unroll
          for (int r = 0; r < 4; r++) o[(size_t)(mr + r) * 1024 + c2] = f2bf(v[r] + bb);
        } else {  // V -> V^T [B=2][H=16][HD=64][L=2048] bf16
          const int vc = col - 2048;
          const float bb = bias3[vc];
          const int h = vc >> 6, d = vc & 63;
          const int b = mr >> 11, l0 = mr & 2047;
          uint2 pk;
          pk.x = f2bf2(v[0] + bb, v[1] + bb);
          pk.y = f2bf2(v[2] + bb, v[3] + bb);
          *(uint2*)((ushort_t*)outp3 + ((((size_t)b * 16 + h) * 64 + d) * 2048 + l0)) = pk;
        }
      } else if constexpr (EPI == EPI_RESID) {
        const float bb = bias[col];
        float* o = (float*)outp;
#pragma unroll
        for (int r = 0; r < 4; r++) {
          size_t idx = (size_t)(mr + r) * N + col;
          o[idx] = resid[idx] + v[r] + bb;
        }
      } else if constexpr (EPI == EPI_GELU) {  // exact GELU, branchless fast erf
        const float bb = bias[col];
        ushort_t* o = (ushort_t*)outp;
#pragma unroll
        for (int r = 0; r < 4; r++)
          o[(size_t)(mr + r) * N + col] = f2bf(gelu_fast(v[r] + bb));
      }
    }
  }
}

// ---------------- 256x256 one-drain-per-tile GEMM (v2), BK=64, 8 waves, 128 KB LDS ----
template <int EPI>
__global__ __launch_bounds__(512, 2) void gemm256v2(
    const ushort_t* __restrict__ A, const ushort_t* __restrict__ Wb,
    const float* __restrict__ bias,
    void* __restrict__ outp, int M, int N, int K, float oscale) {
  __shared__ ushort_t As[2][256 * 64];
  __shared__ ushort_t Bs[2][256 * 64];
  const int t = threadIdx.x;
  const int w = t >> 6, lane = t & 63;
  const int qd = lane >> 4, ql = lane & 15;
  const int wr = w >> 2, wc = w & 3;  // 2(M) x 4(N) wave grid
  int bx = blockIdx.x, by = blockIdx.y;
  xcd_remap(gridDim.x, gridDim.y, bx, by);
  const int m0 = by * 256, n0 = bx * 256;
  const int sw = ql & 7;

  // staging pointers: gload p covers LDS rows [p*64, p*64+64) (512 thr x 16B = 64 rows)
  const ushort_t* pa[4];
  const ushort_t* pb[4];
#pragma unroll
  for (int p = 0; p < 4; p++) {
    const int n = p * 512 + t, row = n >> 3, c = (n & 7) ^ (row & 7);
    pa[p] = A + (size_t)(m0 + row) * K + c * 8;
    pb[p] = Wb + (size_t)(n0 + row) * K + c * 8;
  }

  // prologue: tile 0
#pragma unroll
  for (int p = 0; p < 4; p++) { gload_lds16(pa[p], &As[0][(p * 512 + t) * 8]); pa[p] += 64; }
#pragma unroll
  for (int p = 0; p < 4; p++) { gload_lds16(pb[p], &Bs[0][(p * 512 + t) * 8]); pb[p] += 64; }
  __syncthreads();

  f32x4 acc[8][4] = {};
  const int NT = K / 64;
  int cur = 0;

#define AFREAD(KS)                                                              \
  _Pragma("unroll") for (int i = 0; i < 8; i++)                                 \
      af[i] = *(const bf16x8*)&Ac[(wr * 128 + i * 16 + ql) * 64 +               \
                                  (((KS) * 4 + qd) ^ sw) * 8];
#define BFREAD(KS, NH)                                                          \
  _Pragma("unroll") for (int jj = 0; jj < 2; jj++)                              \
      bf[jj] = *(const bf16x8*)&Bc[(wc * 64 + (NH) * 32 + jj * 16 + ql) * 64 +  \
                                   (((KS) * 4 + qd) ^ sw) * 8];
#define MM(NH)                                                                  \
  __builtin_amdgcn_s_setprio(1);                                                \
  _Pragma("unroll") for (int i = 0; i < 8; i++)                                 \
      _Pragma("unroll") for (int jj = 0; jj < 2; jj++)                          \
          acc[i][(NH) * 2 + jj] = __builtin_amdgcn_mfma_f32_16x16x32_bf16(      \
              af[i], bf[jj], acc[i][(NH) * 2 + jj], 0, 0, 0);                   \
  __builtin_amdgcn_s_setprio(0);

  for (int T = 0; T < NT; ++T) {
    const ushort_t* Ac = As[cur];
    const ushort_t* Bc = Bs[cur];
    ushort_t* An = As[cur ^ 1];
    ushort_t* Bn = Bs[cur ^ 1];
    const bool st = (T + 1 < NT);
    bf16x8 af[8], bf[2];

    // phase 0 (ks0, nh0): stage ALL of tile T+1, read af(ks0)+bf, 16 MFMA
    if (st) {
#pragma unroll
      for (int p = 0; p < 4; p++) { gload_lds16(pa[p], &An[(p * 512 + t) * 8]); pa[p] += 64; }
#pragma unroll
      for (int p = 0; p < 4; p++) { gload_lds16(pb[p], &Bn[(p * 512 + t) * 8]); pb[p] += 64; }
    }
    AFREAD(0)
    BFREAD(0, 0)
    MM(0)
    __builtin_amdgcn_s_barrier();

    // phase 1 (ks0, nh1): af held
    BFREAD(0, 1)
    MM(1)
    __builtin_amdgcn_s_barrier();

    // phase 2 (ks1, nh0)
    AFREAD(1)
    BFREAD(1, 0)
    MM(0)
    __builtin_amdgcn_s_barrier();

    // phase 3 (ks1, nh1): tile-end drain + fenced barrier (buffer swap)
    BFREAD(1, 1)
    MM(1)
    if (st) asm volatile("s_waitcnt vmcnt(0)" ::: "memory");
    __builtin_amdgcn_sched_barrier(0);
    __builtin_amdgcn_s_barrier();
    __builtin_amdgcn_sched_barrier(0);
    cur ^= 1;
  }
#undef AFREAD
#undef BFREAD
#undef MM

#pragma unroll
  for (int i = 0; i < 8; i++) {
    const int mr = m0 + wr * 128 + i * 16 + qd * 4;
#pragma unroll
    for (int j = 0; j < 4; j++) {
      const int col = n0 + wc * 64 + j * 16 + ql;
      f32x4 v = acc[i][j];
      if constexpr (EPI == EPI_GELU) {
        const float bb = bias[col];
        ushort_t* o = (ushort_t*)outp;
#pragma unroll
        for (int r = 0; r < 4; r++)
          o[(size_t)(mr + r) * N + col] = f2bf(gelu_fast(v[r] + bb));
      } else if constexpr (EPI == EPI_BF16) {
        const float bb = bias[col];
        ushort_t* o = (ushort_t*)outp;
#pragma unroll
        for (int r = 0; r < 4; r++)
          o[(size_t)(mr + r) * N + col] = f2bf((v[r] + bb) * oscale);
      }
    }
  }
}

// ---------------- flash attention, softmax-1, fixed m=0, S^T orientation ----------
// QBLK=64 (was 128): grid (32,32) = 1024 blocks = 4/CU (was 512 = 2/CU, grid-starved:
// Occupancy 17.9%, MfmaUtil 22.5%, HBM 4.6% — latency-bound). LDS 40 KB -> 4 blocks/CU
// fits exactly (160 KB). Per wave: 16 Q-rows, accS[4], accO[4], aq[2].
__global__ __launch_bounds__(256, 4) void flash_attn(const ushort_t* __restrict__ Qg,
                                                     const ushort_t* __restrict__ Kg,
                                                     const ushort_t* __restrict__ VTg,
                                                     ushort_t* __restrict__ Og) {
  __shared__ ushort_t QPs[64 * 64];     // 8 KB: Q tile, then P[n][l] (Q dead after hoist)
  __shared__ ushort_t Ks[2][64 * 64];   // 16 KB (dbuf K tile [l][d])
  __shared__ ushort_t Vs[2][64 * 64];   // 16 KB (dbuf V^T tile [d][l])
  const int t = threadIdx.x, w = t >> 6, lane = t & 63;
  const int qd = lane >> 4, ql = lane & 15;
  int bx = blockIdx.x, bh = blockIdx.y;
  xcd_remap(gridDim.x, gridDim.y, bx, bh);
  const int b = bh >> 4, h = bh & 15;
  const int n0 = bx * 64;
  const ushort_t* Qp = Qg + ((size_t)b * 2048 + n0) * 1024 + h * 64;
  const ushort_t* Kp = Kg + (size_t)b * 2048 * 1024 + h * 64;
  const ushort_t* Vp = VTg + (size_t)bh * 64 * 2048;
  const int sw = ql & 7;  // read-side swizzle key

  // hoisted staging pointers: K advances 64 rows, V 64 cols per tile
  const ushort_t* kp2[2];
  const ushort_t* vp2[2];
#pragma unroll
  for (int p = 0; p < 2; p++) {
    int n = p * 256 + t, row = n >> 3, c = (n & 7) ^ (row & 7);
    kp2[p] = Kp + (size_t)row * 1024 + c * 8;
    vp2[p] = Vp + (size_t)row * 2048 + c * 8;
  }

  // stage Q (swizzled, 64 rows) + K/V tile 0
#pragma unroll
  for (int p = 0; p < 2; p++) {
    int n = p * 256 + t, row = n >> 3, c = (n & 7) ^ (row & 7);
    gload_lds16(Qp + (size_t)row * 1024 + c * 8, &QPs[n * 8]);
  }
#pragma unroll
  for (int p = 0; p < 2; p++) {
    int n = p * 256 + t;
    gload_lds16(kp2[p], &Ks[0][n * 8]);
    gload_lds16(vp2[p], &Vs[0][n * 8]);
    kp2[p] += 64 * 1024;
    vp2[p] += 64;
  }
  __syncthreads();

  // hoist Q fragments (loop-invariant); QPs LDS dead afterwards (becomes P)
  bf16x8 aq[2];
#pragma unroll
  for (int ks = 0; ks < 2; ks++)
    aq[ks] = *(const bf16x8*)&QPs[(w * 16 + ql) * 64 + ((ks * 4 + qd) ^ sw) * 8];
  __syncthreads();  // all aq reads done before any wave writes P into QPs

  f32x4 accO[4] = {};
  float lro = 0.f;  // denom partial for n = w*16 + ql (quad-partial over l%16 ranges)

  int cur = 0;
  for (int lt = 0; lt < 32; ++lt) {
    if (lt + 1 < 32) {
#pragma unroll
      for (int p = 0; p < 2; p++) {
        int n = p * 256 + t;
        gload_lds16(kp2[p], &Ks[1 ^ cur][n * 8]);
        gload_lds16(vp2[p], &Vs[1 ^ cur][n * 8]);
        kp2[p] += 64 * 1024;
        vp2[p] += 64;
      }
    }
    const ushort_t* Kc = Ks[cur];
    const ushort_t* Vc = Vs[cur];

    // S^T = K (Q*0.1803)^T : accS[j], rows l = j*16+qd*4+r, cols n = w*16+ql
    f32x4 accS[4] = {};
#pragma unroll
    for (int ks = 0; ks < 2; ks++) {
      bf16x8 bk[4];
#pragma unroll
      for (int j = 0; j < 4; j++)
        bk[j] = *(const bf16x8*)&Kc[(j * 16 + ql) * 64 + ((ks * 4 + qd) ^ sw) * 8];
      __builtin_amdgcn_s_setprio(1);
#pragma unroll
      for (int j = 0; j < 4; j++)
        accS[j] = __builtin_amdgcn_mfma_f32_16x16x32_bf16(bk[j], aq[ks], accS[j], 0, 0, 0);
      __builtin_amdgcn_s_setprio(0);
    }

    // p = exp2(s_hat); denom += p; pack 4 consecutive l -> one b64 P-write
#pragma unroll
    for (int j = 0; j < 4; j++) {
      f32x4 p;
#pragma unroll
      for (int r = 0; r < 4; r++) {
        p[r] = __builtin_amdgcn_exp2f(accS[j][r]);
        lro += p[r];
      }
      const int n = w * 16 + ql;
      // l = j*16 + qd*4 + r; 16B chunk c = j*2 + (qd>>1), swizzled c^(n&7)=c^sw
      const int coff = (((j * 2 + (qd >> 1)) ^ sw) << 3) + ((qd & 1) << 2);
      uint2 pk; pk.x = f2bf2(p[0], p[1]); pk.y = f2bf2(p[2], p[3]);
      *(uint2*)&QPs[n * 64 + coff] = pk;
    }

    // O += P V (P rows intra-wave; V^T B-frags from Vs)
#pragma unroll
    for (int ks = 0; ks < 2; ks++) {
      bf16x8 ap, bv[4];
      ap = *(const bf16x8*)&QPs[(w * 16 + ql) * 64 + ((ks * 4 + qd) ^ sw) * 8];
#pragma unroll
      for (int jo = 0; jo < 4; jo++)
        bv[jo] = *(const bf16x8*)&Vc[(jo * 16 + ql) * 64 + ((ks * 4 + qd) ^ sw) * 8];
      __builtin_amdgcn_s_setprio(1);
#pragma unroll
      for (int jo = 0; jo < 4; jo++)
        accO[jo] = __builtin_amdgcn_mfma_f32_16x16x32_bf16(ap, bv[jo], accO[jo], 0, 0, 0);
      __builtin_amdgcn_s_setprio(0);
    }

    __syncthreads();  // K/V[cur] readers done + next-tile loads drained
    cur ^= 1;
  }

  // finish denominator: sum across quads (each quad held disjoint l%16 ranges)
  float l = lro;
  l += __shfl_xor(l, 16);
  l += __shfl_xor(l, 32);
  const float dn = l + 1.0f;  // +1: implicit zero logit of softmax-1

#pragma unroll
  for (int r = 0; r < 4; r++) {
    // denom for row n' = qd*4+r lives in lane ql = n' (quad-uniform after reduce)
    const float inv = 1.0f / __shfl(dn, qd * 4 + r);
    const int row = n0 + w * 16 + qd * 4 + r;
#pragma unroll
    for (int jo = 0; jo < 4; jo++)
      Og[((size_t)b * 2048 + row) * 1024 + h * 64 + jo * 16 + ql] =
          f2bf(accO[jo][r] * inv);
  }
}

// ---------------- launch ----------------
extern "C" void kernel_launch(void* const* d_in, const int* in_sizes, int n_in,
                              void* d_out, int out_size, void* d_ws, size_t ws_size,
                              hipStream_t stream) {
  const float* x_q = (const float*)d_in[0];
  const float* x_kv = (const float*)d_in[1];
  const float* qn_g = (const float*)d_in[2];
  const float* qn_b = (const float*)d_in[3];
  const float* kvn_g = (const float*)d_in[4];
  const float* kvn_b = (const float*)d_in[5];
  const float* Wq = (const float*)d_in[6];
  const float* bq = (const float*)d_in[7];
  const float* Wk = (const float*)d_in[8];
  const float* bk = (const float*)d_in[9];
  const float* Wv = (const float*)d_in[10];
  const float* bv = (const float*)d_in[11];
  const float* Wo = (const float*)d_in[12];
  const float* bo = (const float*)d_in[13];
  const float* n2_g = (const float*)d_in[14];
  const float* n2_b = (const float*)d_in[15];
  const float* W1 = (const float*)d_in[16];
  const float* b1 = (const float*)d_in[17];
  const float* W2 = (const float*)d_in[18];
  const float* b2 = (const float*)d_in[19];

  char* ws = (char*)d_ws;
  const size_t MB = 1ull << 20;
  ushort_t* WQKVB = (ushort_t*)(ws + 0 * MB);  // 6 MB ([Wq;Wk;Wv], 3072x1024)
  ushort_t* WoB = (ushort_t*)(ws + 6 * MB);    // 2 MB
  ushort_t* W1B = (ushort_t*)(ws + 8 * MB);    // 8 MB
  ushort_t* W2B = (ushort_t*)(ws + 16 * MB);   // 8 MB
  ushort_t* LNQ = (ushort_t*)(ws + 24 * MB);
  ushort_t* LNKV = (ushort_t*)(ws + 32 * MB);
  ushort_t* Qb = (ushort_t*)(ws + 40 * MB);
  ushort_t* Kb = (ushort_t*)(ws + 48 * MB);
  ushort_t* VTb = (ushort_t*)(ws + 56 * MB);
  ushort_t* AOb = (ushort_t*)(ws + 64 * MB);
  float* Xf = (float*)(ws + 72 * MB);          // 16 MB
  ushort_t* LN2 = (ushort_t*)(ws + 88 * MB);
  ushort_t* Hb = (ushort_t*)(ws + 24 * MB);    // 32 MB, overlays LNQ/LNKV/Qb/Kb (dead by MLP1)

  // fold softmax scale (1/8) and exp->exp2 (log2 e) into the Q projection
  const float QSCALE = 0.18033688011112042f;  // 0.125 * log2(e)

  // fused weight conversion + input LayerNorms (one launch, independent work)
  cvt_ln<<<20480, 256, 0, stream>>>(Wq, Wk, Wv, Wo, W1, W2, WQKVB, WoB, W1B, W2B,
                                    x_q, x_kv, qn_g, qn_b, kvn_g, kvn_b, LNQ, LNKV);

  // merged Q+K+V projection: N=3072, A = LNQ for n<1024 else LNKV (verified 128^2)
  gemm_bt<128, 128, 32, EPI_QKV><<<dim3(24, 32), 256, 0, stream>>>(
      LNQ, LNKV, WQKVB, bq, bk, bv, nullptr, Qb, Kb, VTb, 4096, 3072, 1024, QSCALE);

  // flash attention: QBLK=64 -> 1024 blocks (4/CU)
  flash_attn<<<dim3(32, 32), 256, 0, stream>>>(Qb, Kb, VTb, AOb);

  // out-proj: BM=64 tiles -> 1024 blocks (4/CU); verified 2-dbuf structure
  gemm_bt<64, 64, 64, EPI_RESID><<<dim3(16, 64), 256, 0, stream>>>(
      AOb, nullptr, WoB, bo, nullptr, nullptr, x_q, Xf, nullptr, nullptr,
      4096, 1024, 1024, 1.0f);
  ln_bf16<<<4096, 256, 0, stream>>>(Xf, n2_g, n2_b, LN2);
  // MLP up-proj + GELU: 256^2 one-drain-per-tile kernel (grid 16x16 = 1 block/CU)
  gemm256v2<EPI_GELU><<<dim3(16, 16), 512, 0, stream>>>(
      LN2, W1B, b1, Hb, 4096, 4096, 1024, 1.0f);
  gemm_bt<64, 64, 64, EPI_RESID><<<dim3(16, 64), 256, 0, stream>>>(
      Hb, nullptr, W2B, b2, nullptr, nullptr, Xf, (float*)d_out, nullptr, nullptr,
      4096, 1024, 4096, 1.0f);
}

// Round 10
// 352.195 us; speedup vs baseline: 1.0119x; 1.0106x over previous
//
#include <hip/hip_runtime.h>
#include <hip/hip_bf16.h>
#include <stdint.h>

#define DEV __device__ __forceinline__

typedef unsigned short ushort_t;
typedef __attribute__((ext_vector_type(8))) short bf16x8;  // 8 bf16 = 4 VGPRs
typedef __attribute__((ext_vector_type(4))) float f32x4;

// hardware packed f32->bf16 (RNE), 1 VALU inst (gfx950 v_cvt_pk_bf16_f32)
DEV uint32_t f2bf2(float lo, float hi) {
  uint32_t d;
  asm("v_cvt_pk_bf16_f32 %0, %1, %2" : "=v"(d) : "v"(lo), "v"(hi));
  return d;
}
DEV ushort_t f2bf(float f) { return (ushort_t)f2bf2(f, f); }

DEV void gload_lds16(const void* gp, void* lp) {
  __builtin_amdgcn_global_load_lds(
      (__attribute__((address_space(1))) void*)(void*)(uintptr_t)gp,
      (__attribute__((address_space(3))) void*)lp, 16, 0, 0);
}

// exact-GELU via branchless A&S 7.1.26 erf: |erf err| <= 1.5e-7 (invisible after
// bf16 rounding). ~15 VALU ops vs libm erff's ~30+ with branches.
DEV float gelu_fast(float x) {
  const float z = fabsf(x) * 0.70710678118654752f;
  const float t = __builtin_amdgcn_rcpf(fmaf(0.3275911f, z, 1.0f));
  float p = fmaf(1.061405429f, t, -1.453152027f);
  p = fmaf(p, t, 1.421413741f);
  p = fmaf(p, t, -0.284496736f);
  p = fmaf(p, t, 0.254829592f);
  p *= t;
  const float e = __builtin_amdgcn_exp2f(z * z * -1.4426950408889634f);  // e^{-z^2}
  const float er = fmaf(-p, e, 1.0f);                                    // erf(|x|/√2)
  const float s = copysignf(er, x);
  return 0.5f * x * (1.0f + s);
}

// ---------------- fused weight cvt + input LayerNorms (1 launch) ----------------
DEV void ln_row(const float* __restrict__ x, const float* __restrict__ g,
                const float* __restrict__ be, ushort_t* __restrict__ out, int row) {
  const int t = threadIdx.x;
  const float4 v = ((const float4*)(x + (size_t)row * 1024))[t];
  float s = v.x + v.y + v.z + v.w;
  float sq = v.x * v.x + v.y * v.y + v.z * v.z + v.w * v.w;
#pragma unroll
  for (int d = 1; d < 64; d <<= 1) { s += __shfl_xor(s, d); sq += __shfl_xor(sq, d); }
  __shared__ float sm[8];
  const int w = t >> 6, lane = t & 63;
  if (lane == 0) { sm[w * 2] = s; sm[w * 2 + 1] = sq; }
  __syncthreads();
  s = sm[0] + sm[2] + sm[4] + sm[6];
  sq = sm[1] + sm[3] + sm[5] + sm[7];
  const float mean = s * (1.f / 1024.f);
  const float var = sq * (1.f / 1024.f) - mean * mean;
  const float rstd = rsqrtf(var + 1e-5f);
  const float4 gv = ((const float4*)g)[t];
  const float4 bv = ((const float4*)be)[t];
  uint2 o;
  o.x = f2bf2((v.x - mean) * rstd * gv.x + bv.x, (v.y - mean) * rstd * gv.y + bv.y);
  o.y = f2bf2((v.z - mean) * rstd * gv.z + bv.z, (v.w - mean) * rstd * gv.w + bv.w);
  ((uint2*)(out + (size_t)row * 1024))[t] = o;
}

__global__ __launch_bounds__(256) void cvt_ln(
    const float* __restrict__ Wq, const float* __restrict__ Wk,
    const float* __restrict__ Wv, const float* __restrict__ Wo,
    const float* __restrict__ W1, const float* __restrict__ W2,
    ushort_t* __restrict__ WQKVB, ushort_t* __restrict__ WoB,
    ushort_t* __restrict__ W1B, ushort_t* __restrict__ W2B,
    const float* __restrict__ x_q, const float* __restrict__ x_kv,
    const float* __restrict__ qg, const float* __restrict__ qb,
    const float* __restrict__ kg, const float* __restrict__ kb,
    ushort_t* __restrict__ oq, ushort_t* __restrict__ okv) {
  if (blockIdx.x < 12288) {
    int i = blockIdx.x * 256 + threadIdx.x;  // float4 index over concatenated weights
    const float* src; ushort_t* dst; int j;
    if (i < 262144)            { src = Wq; dst = WQKVB;            j = i; }
    else if (i < 524288)       { src = Wk; dst = WQKVB + 1048576;  j = i - 262144; }
    else if (i < 786432)       { src = Wv; dst = WQKVB + 2097152;  j = i - 524288; }
    else if (i < 1048576)      { src = Wo; dst = WoB;              j = i - 786432; }
    else if (i < 2097152)      { src = W1; dst = W1B;              j = i - 1048576; }
    else                       { src = W2; dst = W2B;              j = i - 2097152; }
    float4 v = ((const float4*)src)[j];
    uint2 o; o.x = f2bf2(v.x, v.y); o.y = f2bf2(v.z, v.w);
    ((uint2*)dst)[j] = o;
  } else {
    const int r = blockIdx.x - 12288;
    if (r < 4096) ln_row(x_q, qg, qb, oq, r);
    else ln_row(x_kv, kg, kb, okv, r - 4096);
  }
}

__global__ __launch_bounds__(256) void ln_bf16(const float* __restrict__ x,
                                               const float* __restrict__ g,
                                               const float* __restrict__ be,
                                               ushort_t* __restrict__ out) {
  ln_row(x, g, be, out, blockIdx.x);
}

// XCD swizzle: cyclic wg->XCD dispatch means lin%8 = XCD. Remap so each XCD's
// resident blocks share gy/8 consecutive M-row tiles (A-tile / KV L2 locality).
DEV void xcd_remap(int gx, int gy, int& bx, int& by) {
  const int lin = by * gx + bx;
  const int xcd = lin & 7, s = lin >> 3;
  by = xcd * (gy >> 3) + s / gx;
  bx = s % gx;
}

enum { EPI_BF16 = 0, EPI_KV = 1, EPI_RESID = 2, EPI_GELU = 3, EPI_QKV = 4 };

// ---------------- GEMM (verified R2 structure): out[m,n] = sum_k A[m,k]*W[n,k] ----------
template <int BM, int TN, int BK, int EPI>
__global__ __launch_bounds__(256, (BM == 64) ? 4 : 3) void gemm_bt(
    const ushort_t* __restrict__ A,    // [M][K] bf16
    const ushort_t* __restrict__ A2,   // EPI_QKV: A for n0>=1024 (LNKV)
    const ushort_t* __restrict__ Wb,   // [N][K] bf16
    const float* __restrict__ bias, const float* __restrict__ bias2,
    const float* __restrict__ bias3,
    const float* __restrict__ resid,   // [M][N] f32 or null
    void* __restrict__ outp, void* __restrict__ outp2, void* __restrict__ outp3,
    int M, int N, int K, float oscale) {
  constexpr int WAVES_N = (TN == 128 || BM == 64) ? 2 : 1;
  constexpr int WAVES_M = 4 / WAVES_N;
  constexpr int NI = BM / WAVES_M / 16;  // M-frags per wave
  constexpr int NJ = TN / WAVES_N / 16;  // N-frags per wave
  constexpr int CH = BK / 8;             // 16B chunks per row
  constexpr int NA = (BM * CH) / 256;    // A staging loads per thread
  constexpr int NBL = (TN * CH) / 256;   // B staging loads per thread
  constexpr int KS = BK / 32;            // mfma K-steps per tile
  __shared__ ushort_t As[2][BM * BK];
  __shared__ ushort_t Bs[2][TN * BK];
  const int t = threadIdx.x;
  const int w = t >> 6, lane = t & 63;
  const int qd = lane >> 4, ql = lane & 15;
  int bx = blockIdx.x, by = blockIdx.y;
  xcd_remap(gridDim.x, gridDim.y, bx, by);
  const int m0 = by * BM, n0 = bx * TN;
  const int wm = (w / WAVES_N) * (BM / WAVES_M);
  const int wn = (w % WAVES_N) * (TN / WAVES_N);
  const int sw = (BK == 64) ? (ql & 7) : ((ql >> 1) & 3);  // read-side swizzle key

  const ushort_t* Ause = (EPI == EPI_QKV && n0 >= 1024) ? A2 : A;

  // hoisted staging pointers (advance by BK elems per iter); source chunk swizzled
  const ushort_t* pa[NA];
#pragma unroll
  for (int p = 0; p < NA; p++) {
    int n = p * 256 + t, row = n / CH, c = n % CH;
    int g = (BK == 64) ? (c ^ (row & 7)) : (c ^ ((row >> 1) & 3));
    pa[p] = Ause + (size_t)(m0 + row) * K + g * 8;
  }
  const ushort_t* pb[NBL];
#pragma unroll
  for (int p = 0; p < NBL; p++) {
    int n = p * 256 + t, row = n / CH, c = n % CH;
    int g = (BK == 64) ? (c ^ (row & 7)) : (c ^ ((row >> 1) & 3));
    pb[p] = Wb + (size_t)(n0 + row) * K + g * 8;
  }

  // preload tile 0
#pragma unroll
  for (int p = 0; p < NA; p++) { gload_lds16(pa[p], &As[0][(p * 256 + t) * 8]); pa[p] += BK; }
#pragma unroll
  for (int p = 0; p < NBL; p++) { gload_lds16(pb[p], &Bs[0][(p * 256 + t) * 8]); pb[p] += BK; }
  __syncthreads();

  f32x4 acc[NI][NJ] = {};
  const int NIT = K / BK;
  int cur = 0;

  for (int it = 0; it < NIT; ++it) {
    if (it + 1 < NIT) {  // prefetch next tile into the other buffer
#pragma unroll
      for (int p = 0; p < NA; p++) { gload_lds16(pa[p], &As[1 ^ cur][(p * 256 + t) * 8]); pa[p] += BK; }
#pragma unroll
      for (int p = 0; p < NBL; p++) { gload_lds16(pb[p], &Bs[1 ^ cur][(p * 256 + t) * 8]); pb[p] += BK; }
    }
    const ushort_t* Ac = As[cur];
    const ushort_t* Bc = Bs[cur];
#pragma unroll
    for (int ks = 0; ks < KS; ks++) {
      bf16x8 af[NI], bf[NJ];
#pragma unroll
      for (int i = 0; i < NI; i++)
        af[i] = *(const bf16x8*)&Ac[(wm + i * 16 + ql) * BK + ((ks * 4 + qd) ^ sw) * 8];
#pragma unroll
      for (int j = 0; j < NJ; j++)
        bf[j] = *(const bf16x8*)&Bc[(wn + j * 16 + ql) * BK + ((ks * 4 + qd) ^ sw) * 8];
#pragma unroll
      for (int i = 0; i < NI; i++)
#pragma unroll
        for (int j = 0; j < NJ; j++)
          acc[i][j] = __builtin_amdgcn_mfma_f32_16x16x32_bf16(af[i], bf[j], acc[i][j], 0, 0, 0);
    }
    __syncthreads();  // readers of cur done + prefetch drained
    cur ^= 1;
  }

#pragma unroll
  for (int i = 0; i < NI; i++) {
    const int mr = m0 + wm + i * 16 + qd * 4;
#pragma unroll
    for (int j = 0; j < NJ; j++) {
      const int col = n0 + wn + j * 16 + ql;
      f32x4 v = acc[i][j];
      if constexpr (EPI == EPI_BF16) {
        const float bb = bias[col];
        ushort_t* o = (ushort_t*)outp;
#pragma unroll
        for (int r = 0; r < 4; r++) o[(size_t)(mr + r) * N + col] = f2bf((v[r] + bb) * oscale);
      } else if constexpr (EPI == EPI_QKV) {
        if (col < 1024) {  // Q half (pre-scaled by oscale for exp2 softmax)
          const float bb = bias[col];
          ushort_t* o = (ushort_t*)outp;
#pragma unroll
          for (int r = 0; r < 4; r++) o[(size_t)(mr + r) * 1024 + col] = f2bf((v[r] + bb) * oscale);
        } else if (col < 2048) {  // K -> [4096][1024] bf16
          const int c2 = col - 1024;
          const float bb = bias2[c2];
          ushort_t* o = (ushort_t*)outp2;
#pragma unroll
          for (int r = 0; r < 4; r++) o[(size_t)(mr + r) * 1024 + c2] = f2bf(v[r] + bb);
        } else {  // V -> V^T [B=2][H=16][HD=64][L=2048] bf16
          const int vc = col - 2048;
          const float bb = bias3[vc];
          const int h = vc >> 6, d = vc & 63;
          const int b = mr >> 11, l0 = mr & 2047;
          uint2 pk;
          pk.x = f2bf2(v[0] + bb, v[1] + bb);
          pk.y = f2bf2(v[2] + bb, v[3] + bb);
          *(uint2*)((ushort_t*)outp3 + ((((size_t)b * 16 + h) * 64 + d) * 2048 + l0)) = pk;
        }
      } else if constexpr (EPI == EPI_RESID) {
        const float bb = bias[col];
        float* o = (float*)outp;
#pragma unroll
        for (int r = 0; r < 4; r++) {
          size_t idx = (size_t)(mr + r) * N + col;
          o[idx] = resid[idx] + v[r] + bb;
        }
      } else if constexpr (EPI == EPI_GELU) {  // exact GELU, branchless fast erf
        const float bb = bias[col];
        ushort_t* o = (ushort_t*)outp;
#pragma unroll
        for (int r = 0; r < 4; r++)
          o[(size_t)(mr + r) * N + col] = f2bf(gelu_fast(v[r] + bb));
      }
    }
  }
}

// ---------------- 256x256 one-drain-per-tile GEMM (v2), BK=64, 8 waves, 128 KB LDS ----
template <int EPI>
__global__ __launch_bounds__(512, 2) void gemm256v2(
    const ushort_t* __restrict__ A, const ushort_t* __restrict__ Wb,
    const float* __restrict__ bias,
    void* __restrict__ outp, int M, int N, int K, float oscale) {
  __shared__ ushort_t As[2][256 * 64];
  __shared__ ushort_t Bs[2][256 * 64];
  const int t = threadIdx.x;
  const int w = t >> 6, lane = t & 63;
  const int qd = lane >> 4, ql = lane & 15;
  const int wr = w >> 2, wc = w & 3;  // 2(M) x 4(N) wave grid
  int bx = blockIdx.x, by = blockIdx.y;
  xcd_remap(gridDim.x, gridDim.y, bx, by);
  const int m0 = by * 256, n0 = bx * 256;
  const int sw = ql & 7;

  // staging pointers: gload p covers LDS rows [p*64, p*64+64) (512 thr x 16B = 64 rows)
  const ushort_t* pa[4];
  const ushort_t* pb[4];
#pragma unroll
  for (int p = 0; p < 4; p++) {
    const int n = p * 512 + t, row = n >> 3, c = (n & 7) ^ (row & 7);
    pa[p] = A + (size_t)(m0 + row) * K + c * 8;
    pb[p] = Wb + (size_t)(n0 + row) * K + c * 8;
  }

  // prologue: tile 0
#pragma unroll
  for (int p = 0; p < 4; p++) { gload_lds16(pa[p], &As[0][(p * 512 + t) * 8]); pa[p] += 64; }
#pragma unroll
  for (int p = 0; p < 4; p++) { gload_lds16(pb[p], &Bs[0][(p * 512 + t) * 8]); pb[p] += 64; }
  __syncthreads();

  f32x4 acc[8][4] = {};
  const int NT = K / 64;
  int cur = 0;

#define AFREAD(KS)                                                              \
  _Pragma("unroll") for (int i = 0; i < 8; i++)                                 \
      af[i] = *(const bf16x8*)&Ac[(wr * 128 + i * 16 + ql) * 64 +               \
                                  (((KS) * 4 + qd) ^ sw) * 8];
#define BFREAD(KS, NH)                                                          \
  _Pragma("unroll") for (int jj = 0; jj < 2; jj++)                              \
      bf[jj] = *(const bf16x8*)&Bc[(wc * 64 + (NH) * 32 + jj * 16 + ql) * 64 +  \
                                   (((KS) * 4 + qd) ^ sw) * 8];
#define MM(NH)                                                                  \
  __builtin_amdgcn_s_setprio(1);                                                \
  _Pragma("unroll") for (int i = 0; i < 8; i++)                                 \
      _Pragma("unroll") for (int jj = 0; jj < 2; jj++)                          \
          acc[i][(NH) * 2 + jj] = __builtin_amdgcn_mfma_f32_16x16x32_bf16(      \
              af[i], bf[jj], acc[i][(NH) * 2 + jj], 0, 0, 0);                   \
  __builtin_amdgcn_s_setprio(0);

  for (int T = 0; T < NT; ++T) {
    const ushort_t* Ac = As[cur];
    const ushort_t* Bc = Bs[cur];
    ushort_t* An = As[cur ^ 1];
    ushort_t* Bn = Bs[cur ^ 1];
    const bool st = (T + 1 < NT);
    bf16x8 af[8], bf[2];

    // phase 0 (ks0, nh0): stage ALL of tile T+1, read af(ks0)+bf, 16 MFMA
    if (st) {
#pragma unroll
      for (int p = 0; p < 4; p++) { gload_lds16(pa[p], &An[(p * 512 + t) * 8]); pa[p] += 64; }
#pragma unroll
      for (int p = 0; p < 4; p++) { gload_lds16(pb[p], &Bn[(p * 512 + t) * 8]); pb[p] += 64; }
    }
    AFREAD(0)
    BFREAD(0, 0)
    MM(0)
    __builtin_amdgcn_s_barrier();

    // phase 1 (ks0, nh1): af held
    BFREAD(0, 1)
    MM(1)
    __builtin_amdgcn_s_barrier();

    // phase 2 (ks1, nh0)
    AFREAD(1)
    BFREAD(1, 0)
    MM(0)
    __builtin_amdgcn_s_barrier();

    // phase 3 (ks1, nh1): tile-end drain + fenced barrier (buffer swap)
    BFREAD(1, 1)
    MM(1)
    if (st) asm volatile("s_waitcnt vmcnt(0)" ::: "memory");
    __builtin_amdgcn_sched_barrier(0);
    __builtin_amdgcn_s_barrier();
    __builtin_amdgcn_sched_barrier(0);
    cur ^= 1;
  }
#undef AFREAD
#undef BFREAD
#undef MM

#pragma unroll
  for (int i = 0; i < 8; i++) {
    const int mr = m0 + wr * 128 + i * 16 + qd * 4;
#pragma unroll
    for (int j = 0; j < 4; j++) {
      const int col = n0 + wc * 64 + j * 16 + ql;
      f32x4 v = acc[i][j];
      if constexpr (EPI == EPI_GELU) {
        const float bb = bias[col];
        ushort_t* o = (ushort_t*)outp;
#pragma unroll
        for (int r = 0; r < 4; r++)
          o[(size_t)(mr + r) * N + col] = f2bf(gelu_fast(v[r] + bb));
      } else if constexpr (EPI == EPI_BF16) {
        const float bb = bias[col];
        ushort_t* o = (ushort_t*)outp;
#pragma unroll
        for (int r = 0; r < 4; r++)
          o[(size_t)(mr + r) * N + col] = f2bf((v[r] + bb) * oscale);
      }
    }
  }
}

// ---------------- flash attention with softmax-1, fixed m=0, S^T orientation ------
// Q pre-scaled by 0.125*log2(e) in the QKV projection; p = exp2(s_hat) = exp(q.k/8).
// S^T = K.Q^T (swapped MFMA operands) so P packs into b64 LDS writes. XCD swizzle
// groups 4 heads per XCD -> K/V working set 2 MB fits the 4 MB per-XCD L2.
__global__ __launch_bounds__(256, 2) void flash_attn(const ushort_t* __restrict__ Qg,
                                                     const ushort_t* __restrict__ Kg,
                                                     const ushort_t* __restrict__ VTg,
                                                     ushort_t* __restrict__ Og) {
  __shared__ ushort_t QPs[128 * 64];    // 16 KB: Q tile, then P[n][l] (Q dead after hoist)
  __shared__ ushort_t Ks[2][64 * 64];   // 16 KB (dbuf K tile [l][d])
  __shared__ ushort_t Vs[2][64 * 64];   // 16 KB (dbuf V^T tile [d][l])
  const int t = threadIdx.x, w = t >> 6, lane = t & 63;
  const int qd = lane >> 4, ql = lane & 15;
  int bx = blockIdx.x, bh = blockIdx.y;
  xcd_remap(gridDim.x, gridDim.y, bx, bh);
  const int b = bh >> 4, h = bh & 15;
  const int n0 = bx * 128;
  const ushort_t* Qp = Qg + ((size_t)b * 2048 + n0) * 1024 + h * 64;
  const ushort_t* Kp = Kg + (size_t)b * 2048 * 1024 + h * 64;
  const ushort_t* Vp = VTg + (size_t)bh * 64 * 2048;
  const int sw = ql & 7;  // read-side swizzle key

  // hoisted staging pointers: K advances 64 rows, V 64 cols per tile
  const ushort_t* kp2[2];
  const ushort_t* vp2[2];
#pragma unroll
  for (int p = 0; p < 2; p++) {
    int n = p * 256 + t, row = n >> 3, c = (n & 7) ^ (row & 7);
    kp2[p] = Kp + (size_t)row * 1024 + c * 8;
    vp2[p] = Vp + (size_t)row * 2048 + c * 8;
  }

  // stage Q (swizzled) + K/V tile 0
#pragma unroll
  for (int p = 0; p < 4; p++) {
    int n = p * 256 + t, row = n >> 3, c = (n & 7) ^ (row & 7);
    gload_lds16(Qp + (size_t)row * 1024 + c * 8, &QPs[n * 8]);
  }
#pragma unroll
  for (int p = 0; p < 2; p++) {
    int n = p * 256 + t;
    gload_lds16(kp2[p], &Ks[0][n * 8]);
    gload_lds16(vp2[p], &Vs[0][n * 8]);
    kp2[p] += 64 * 1024;
    vp2[p] += 64;
  }
  __syncthreads();

  // hoist Q fragments (loop-invariant); Qs LDS dead afterwards
  bf16x8 aq[2][2];
#pragma unroll
  for (int i = 0; i < 2; i++)
#pragma unroll
    for (int ks = 0; ks < 2; ks++)
      aq[i][ks] = *(const bf16x8*)&QPs[(w * 32 + i * 16 + ql) * 64 + ((ks * 4 + qd) ^ sw) * 8];
  __syncthreads();  // all aq reads done before any wave writes P into QPs

  f32x4 accO[2][4] = {};
  float lro2[2] = {0.f, 0.f};  // denom partials for n = w*32 + i*16 + ql (quad-partial)

  int cur = 0;
  for (int lt = 0; lt < 32; ++lt) {
    if (lt + 1 < 32) {
#pragma unroll
      for (int p = 0; p < 2; p++) {
        int n = p * 256 + t;
        gload_lds16(kp2[p], &Ks[1 ^ cur][n * 8]);
        gload_lds16(vp2[p], &Vs[1 ^ cur][n * 8]);
        kp2[p] += 64 * 1024;
        vp2[p] += 64;
      }
    }
    const ushort_t* Kc = Ks[cur];
    const ushort_t* Vc = Vs[cur];

    // S^T = K (Q*0.1803)^T : accS[j][i], rows l = j*16+qd*4+r, cols n = i*16+ql
    f32x4 accS[4][2] = {};
#pragma unroll
    for (int ks = 0; ks < 2; ks++) {
      bf16x8 bk[4];
#pragma unroll
      for (int j = 0; j < 4; j++)
        bk[j] = *(const bf16x8*)&Kc[(j * 16 + ql) * 64 + ((ks * 4 + qd) ^ sw) * 8];
      __builtin_amdgcn_s_setprio(1);
#pragma unroll
      for (int j = 0; j < 4; j++)
#pragma unroll
        for (int i = 0; i < 2; i++)
          accS[j][i] = __builtin_amdgcn_mfma_f32_16x16x32_bf16(bk[j], aq[i][ks], accS[j][i], 0, 0, 0);
      __builtin_amdgcn_s_setprio(0);
    }

    // p = exp2(s_hat); denom += p; pack 4 consecutive l -> one b64 P-write
#pragma unroll
    for (int j = 0; j < 4; j++)
#pragma unroll
      for (int i = 0; i < 2; i++) {
        f32x4 p;
#pragma unroll
        for (int r = 0; r < 4; r++) {
          p[r] = __builtin_amdgcn_exp2f(accS[j][i][r]);
          lro2[i] += p[r];
        }
        const int n = w * 32 + i * 16 + ql;
        // l = j*16 + qd*4 + r; 16B chunk c = j*2 + (qd>>1), swizzled c^(n&7)=c^sw
        const int coff = (((j * 2 + (qd >> 1)) ^ sw) << 3) + ((qd & 1) << 2);
        uint2 pk; pk.x = f2bf2(p[0], p[1]); pk.y = f2bf2(p[2], p[3]);
        *(uint2*)&QPs[n * 64 + coff] = pk;
      }

    // O += P V (P rows intra-wave; V^T B-frags from Vs)
#pragma unroll
    for (int ks = 0; ks < 2; ks++) {
      bf16x8 ap[2], bv[4];
#pragma unroll
      for (int i = 0; i < 2; i++)
        ap[i] = *(const bf16x8*)&QPs[(w * 32 + i * 16 + ql) * 64 + ((ks * 4 + qd) ^ sw) * 8];
#pragma unroll
      for (int jo = 0; jo < 4; jo++)
        bv[jo] = *(const bf16x8*)&Vc[(jo * 16 + ql) * 64 + ((ks * 4 + qd) ^ sw) * 8];
      __builtin_amdgcn_s_setprio(1);
#pragma unroll
      for (int i = 0; i < 2; i++)
#pragma unroll
        for (int jo = 0; jo < 4; jo++)
          accO[i][jo] = __builtin_amdgcn_mfma_f32_16x16x32_bf16(ap[i], bv[jo], accO[i][jo], 0, 0, 0);
      __builtin_amdgcn_s_setprio(0);
    }

    __syncthreads();  // K/V[cur] readers done + next-tile loads drained
    cur ^= 1;
  }

  // finish denominators: sum across quads (each quad held disjoint l ranges)
  float dn[2];
#pragma unroll
  for (int i = 0; i < 2; i++) {
    float l = lro2[i];
    l += __shfl_xor(l, 16);
    l += __shfl_xor(l, 32);
    dn[i] = l + 1.0f;  // +1: implicit zero logit of softmax-1
  }

#pragma unroll
  for (int i = 0; i < 2; i++)
#pragma unroll
    for (int r = 0; r < 4; r++) {
      // denom for row n' = qd*4+r lives in lane ql = n' (quad-uniform after reduce)
      const float inv = 1.0f / __shfl(dn[i], qd * 4 + r);
      const int row = n0 + w * 32 + i * 16 + qd * 4 + r;
#pragma unroll
      for (int jo = 0; jo < 4; jo++)
        Og[((size_t)b * 2048 + row) * 1024 + h * 64 + jo * 16 + ql] =
            f2bf(accO[i][jo][r] * inv);
    }
}

// ---------------- launch ----------------
extern "C" void kernel_launch(void* const* d_in, const int* in_sizes, int n_in,
                              void* d_out, int out_size, void* d_ws, size_t ws_size,
                              hipStream_t stream) {
  const float* x_q = (const float*)d_in[0];
  const float* x_kv = (const float*)d_in[1];
  const float* qn_g = (const float*)d_in[2];
  const float* qn_b = (const float*)d_in[3];
  const float* kvn_g = (const float*)d_in[4];
  const float* kvn_b = (const float*)d_in[5];
  const float* Wq = (const float*)d_in[6];
  const float* bq = (const float*)d_in[7];
  const float* Wk = (const float*)d_in[8];
  const float* bk = (const float*)d_in[9];
  const float* Wv = (const float*)d_in[10];
  const float* bv = (const float*)d_in[11];
  const float* Wo = (const float*)d_in[12];
  const float* bo = (const float*)d_in[13];
  const float* n2_g = (const float*)d_in[14];
  const float* n2_b = (const float*)d_in[15];
  const float* W1 = (const float*)d_in[16];
  const float* b1 = (const float*)d_in[17];
  const float* W2 = (const float*)d_in[18];
  const float* b2 = (const float*)d_in[19];

  char* ws = (char*)d_ws;
  const size_t MB = 1ull << 20;
  ushort_t* WQKVB = (ushort_t*)(ws + 0 * MB);  // 6 MB ([Wq;Wk;Wv], 3072x1024)
  ushort_t* WoB = (ushort_t*)(ws + 6 * MB);    // 2 MB
  ushort_t* W1B = (ushort_t*)(ws + 8 * MB);    // 8 MB
  ushort_t* W2B = (ushort_t*)(ws + 16 * MB);   // 8 MB
  ushort_t* LNQ = (ushort_t*)(ws + 24 * MB);
  ushort_t* LNKV = (ushort_t*)(ws + 32 * MB);
  ushort_t* Qb = (ushort_t*)(ws + 40 * MB);
  ushort_t* Kb = (ushort_t*)(ws + 48 * MB);
  ushort_t* VTb = (ushort_t*)(ws + 56 * MB);
  ushort_t* AOb = (ushort_t*)(ws + 64 * MB);
  float* Xf = (float*)(ws + 72 * MB);          // 16 MB
  ushort_t* LN2 = (ushort_t*)(ws + 88 * MB);
  ushort_t* Hb = (ushort_t*)(ws + 24 * MB);    // 32 MB, overlays LNQ/LNKV/Qb/Kb (dead by MLP1)

  // fold softmax scale (1/8) and exp->exp2 (log2 e) into the Q projection
  const float QSCALE = 0.18033688011112042f;  // 0.125 * log2(e)

  // fused weight conversion + input LayerNorms (one launch, independent work)
  cvt_ln<<<20480, 256, 0, stream>>>(Wq, Wk, Wv, Wo, W1, W2, WQKVB, WoB, W1B, W2B,
                                    x_q, x_kv, qn_g, qn_b, kvn_g, kvn_b, LNQ, LNKV);

  // merged Q+K+V projection: N=3072, A = LNQ for n<1024 else LNKV (verified 128^2)
  gemm_bt<128, 128, 32, EPI_QKV><<<dim3(24, 32), 256, 0, stream>>>(
      LNQ, LNKV, WQKVB, bq, bk, bv, nullptr, Qb, Kb, VTb, 4096, 3072, 1024, QSCALE);

  flash_attn<<<dim3(16, 32), 256, 0, stream>>>(Qb, Kb, VTb, AOb);

  // out-proj: BM=64 tiles -> 1024 blocks (4/CU); verified 2-dbuf structure
  gemm_bt<64, 64, 64, EPI_RESID><<<dim3(16, 64), 256, 0, stream>>>(
      AOb, nullptr, WoB, bo, nullptr, nullptr, x_q, Xf, nullptr, nullptr,
      4096, 1024, 1024, 1.0f);
  ln_bf16<<<4096, 256, 0, stream>>>(Xf, n2_g, n2_b, LN2);
  // MLP up-proj + GELU: 256^2 one-drain-per-tile kernel (grid 16x16 = 1 block/CU)
  gemm256v2<EPI_GELU><<<dim3(16, 16), 512, 0, stream>>>(
      LN2, W1B, b1, Hb, 4096, 4096, 1024, 1.0f);
  gemm_bt<64, 64, 64, EPI_RESID><<<dim3(16, 64), 256, 0, stream>>>(
      Hb, nullptr, W2B, b2, nullptr, nullptr, Xf, (float*)d_out, nullptr, nullptr,
      4096, 1024, 4096, 1.0f);
}

// Round 11
// 348.044 us; speedup vs baseline: 1.0240x; 1.0119x over previous
//
#include <hip/hip_runtime.h>
#include <hip/hip_bf16.h>
#include <stdint.h>

#define DEV __device__ __forceinline__

typedef unsigned short ushort_t;
typedef __attribute__((ext_vector_type(8))) short bf16x8;  // 8 bf16 = 4 VGPRs
typedef __attribute__((ext_vector_type(4))) float f32x4;

// hardware packed f32->bf16 (RNE), 1 VALU inst (gfx950 v_cvt_pk_bf16_f32)
DEV uint32_t f2bf2(float lo, float hi) {
  uint32_t d;
  asm("v_cvt_pk_bf16_f32 %0, %1, %2" : "=v"(d) : "v"(lo), "v"(hi));
  return d;
}
DEV ushort_t f2bf(float f) { return (ushort_t)f2bf2(f, f); }

DEV void gload_lds16(const void* gp, void* lp) {
  __builtin_amdgcn_global_load_lds(
      (__attribute__((address_space(1))) void*)(void*)(uintptr_t)gp,
      (__attribute__((address_space(3))) void*)lp, 16, 0, 0);
}

// exact-GELU via branchless A&S 7.1.26 erf: |erf err| <= 1.5e-7 (invisible after
// bf16 rounding). ~15 VALU ops vs libm erff's ~30+ with branches.
DEV float gelu_fast(float x) {
  const float z = fabsf(x) * 0.70710678118654752f;
  const float t = __builtin_amdgcn_rcpf(fmaf(0.3275911f, z, 1.0f));
  float p = fmaf(1.061405429f, t, -1.453152027f);
  p = fmaf(p, t, 1.421413741f);
  p = fmaf(p, t, -0.284496736f);
  p = fmaf(p, t, 0.254829592f);
  p *= t;
  const float e = __builtin_amdgcn_exp2f(z * z * -1.4426950408889634f);  // e^{-z^2}
  const float er = fmaf(-p, e, 1.0f);                                    // erf(|x|/√2)
  const float s = copysignf(er, x);
  return 0.5f * x * (1.0f + s);
}

// ---------------- fused weight cvt + input LayerNorms (1 launch) ----------------
DEV void ln_row(const float* __restrict__ x, const float* __restrict__ g,
                const float* __restrict__ be, ushort_t* __restrict__ out, int row) {
  const int t = threadIdx.x;
  const float4 v = ((const float4*)(x + (size_t)row * 1024))[t];
  float s = v.x + v.y + v.z + v.w;
  float sq = v.x * v.x + v.y * v.y + v.z * v.z + v.w * v.w;
#pragma unroll
  for (int d = 1; d < 64; d <<= 1) { s += __shfl_xor(s, d); sq += __shfl_xor(sq, d); }
  __shared__ float sm[8];
  const int w = t >> 6, lane = t & 63;
  if (lane == 0) { sm[w * 2] = s; sm[w * 2 + 1] = sq; }
  __syncthreads();
  s = sm[0] + sm[2] + sm[4] + sm[6];
  sq = sm[1] + sm[3] + sm[5] + sm[7];
  const float mean = s * (1.f / 1024.f);
  const float var = sq * (1.f / 1024.f) - mean * mean;
  const float rstd = rsqrtf(var + 1e-5f);
  const float4 gv = ((const float4*)g)[t];
  const float4 bv = ((const float4*)be)[t];
  uint2 o;
  o.x = f2bf2((v.x - mean) * rstd * gv.x + bv.x, (v.y - mean) * rstd * gv.y + bv.y);
  o.y = f2bf2((v.z - mean) * rstd * gv.z + bv.z, (v.w - mean) * rstd * gv.w + bv.w);
  ((uint2*)(out + (size_t)row * 1024))[t] = o;
}

__global__ __launch_bounds__(256) void cvt_ln(
    const float* __restrict__ Wq, const float* __restrict__ Wk,
    const float* __restrict__ Wv, const float* __restrict__ Wo,
    const float* __restrict__ W1, const float* __restrict__ W2,
    ushort_t* __restrict__ WQKVB, ushort_t* __restrict__ WoB,
    ushort_t* __restrict__ W1B, ushort_t* __restrict__ W2B,
    const float* __restrict__ x_q, const float* __restrict__ x_kv,
    const float* __restrict__ qg, const float* __restrict__ qb,
    const float* __restrict__ kg, const float* __restrict__ kb,
    ushort_t* __restrict__ oq, ushort_t* __restrict__ okv) {
  if (blockIdx.x < 12288) {
    int i = blockIdx.x * 256 + threadIdx.x;  // float4 index over concatenated weights
    const float* src; ushort_t* dst; int j;
    if (i < 262144)            { src = Wq; dst = WQKVB;            j = i; }
    else if (i < 524288)       { src = Wk; dst = WQKVB + 1048576;  j = i - 262144; }
    else if (i < 786432)       { src = Wv; dst = WQKVB + 2097152;  j = i - 524288; }
    else if (i < 1048576)      { src = Wo; dst = WoB;              j = i - 786432; }
    else if (i < 2097152)      { src = W1; dst = W1B;              j = i - 1048576; }
    else                       { src = W2; dst = W2B;              j = i - 2097152; }
    float4 v = ((const float4*)src)[j];
    uint2 o; o.x = f2bf2(v.x, v.y); o.y = f2bf2(v.z, v.w);
    ((uint2*)dst)[j] = o;
  } else {
    const int r = blockIdx.x - 12288;
    if (r < 4096) ln_row(x_q, qg, qb, oq, r);
    else ln_row(x_kv, kg, kb, okv, r - 4096);
  }
}

__global__ __launch_bounds__(256) void ln_bf16(const float* __restrict__ x,
                                               const float* __restrict__ g,
                                               const float* __restrict__ be,
                                               ushort_t* __restrict__ out) {
  ln_row(x, g, be, out, blockIdx.x);
}

// XCD swizzle: cyclic wg->XCD dispatch means lin%8 = XCD. Remap so each XCD's
// resident blocks share gy/8 consecutive M-row tiles (A-tile / KV L2 locality).
DEV void xcd_remap(int gx, int gy, int& bx, int& by) {
  const int lin = by * gx + bx;
  const int xcd = lin & 7, s = lin >> 3;
  by = xcd * (gy >> 3) + s / gx;
  bx = s % gx;
}

enum { EPI_BF16 = 0, EPI_KV = 1, EPI_RESID = 2, EPI_GELU = 3, EPI_QKV = 4 };

// ---------------- GEMM (verified R2 structure): out[m,n] = sum_k A[m,k]*W[n,k] ----------
template <int BM, int TN, int BK, int EPI>
__global__ __launch_bounds__(256, (BM == 64) ? 4 : 3) void gemm_bt(
    const ushort_t* __restrict__ A,    // [M][K] bf16
    const ushort_t* __restrict__ A2,   // EPI_QKV: A for n0>=1024 (LNKV)
    const ushort_t* __restrict__ Wb,   // [N][K] bf16
    const float* __restrict__ bias, const float* __restrict__ bias2,
    const float* __restrict__ bias3,
    const float* __restrict__ resid,   // [M][N] f32 or null
    void* __restrict__ outp, void* __restrict__ outp2, void* __restrict__ outp3,
    int M, int N, int K, float oscale) {
  constexpr int WAVES_N = (TN == 128 || BM == 64) ? 2 : 1;
  constexpr int WAVES_M = 4 / WAVES_N;
  constexpr int NI = BM / WAVES_M / 16;  // M-frags per wave
  constexpr int NJ = TN / WAVES_N / 16;  // N-frags per wave
  constexpr int CH = BK / 8;             // 16B chunks per row
  constexpr int NA = (BM * CH) / 256;    // A staging loads per thread
  constexpr int NBL = (TN * CH) / 256;   // B staging loads per thread
  constexpr int KS = BK / 32;            // mfma K-steps per tile
  __shared__ ushort_t As[2][BM * BK];
  __shared__ ushort_t Bs[2][TN * BK];
  const int t = threadIdx.x;
  const int w = t >> 6, lane = t & 63;
  const int qd = lane >> 4, ql = lane & 15;
  int bx = blockIdx.x, by = blockIdx.y;
  xcd_remap(gridDim.x, gridDim.y, bx, by);
  const int m0 = by * BM, n0 = bx * TN;
  const int wm = (w / WAVES_N) * (BM / WAVES_M);
  const int wn = (w % WAVES_N) * (TN / WAVES_N);
  const int sw = (BK == 64) ? (ql & 7) : ((ql >> 1) & 3);  // read-side swizzle key

  const ushort_t* Ause = (EPI == EPI_QKV && n0 >= 1024) ? A2 : A;

  // hoisted staging pointers (advance by BK elems per iter); source chunk swizzled
  const ushort_t* pa[NA];
#pragma unroll
  for (int p = 0; p < NA; p++) {
    int n = p * 256 + t, row = n / CH, c = n % CH;
    int g = (BK == 64) ? (c ^ (row & 7)) : (c ^ ((row >> 1) & 3));
    pa[p] = Ause + (size_t)(m0 + row) * K + g * 8;
  }
  const ushort_t* pb[NBL];
#pragma unroll
  for (int p = 0; p < NBL; p++) {
    int n = p * 256 + t, row = n / CH, c = n % CH;
    int g = (BK == 64) ? (c ^ (row & 7)) : (c ^ ((row >> 1) & 3));
    pb[p] = Wb + (size_t)(n0 + row) * K + g * 8;
  }

  // preload tile 0
#pragma unroll
  for (int p = 0; p < NA; p++) { gload_lds16(pa[p], &As[0][(p * 256 + t) * 8]); pa[p] += BK; }
#pragma unroll
  for (int p = 0; p < NBL; p++) { gload_lds16(pb[p], &Bs[0][(p * 256 + t) * 8]); pb[p] += BK; }
  __syncthreads();

  f32x4 acc[NI][NJ] = {};
  const int NIT = K / BK;
  int cur = 0;

  for (int it = 0; it < NIT; ++it) {
    if (it + 1 < NIT) {  // prefetch next tile into the other buffer
#pragma unroll
      for (int p = 0; p < NA; p++) { gload_lds16(pa[p], &As[1 ^ cur][(p * 256 + t) * 8]); pa[p] += BK; }
#pragma unroll
      for (int p = 0; p < NBL; p++) { gload_lds16(pb[p], &Bs[1 ^ cur][(p * 256 + t) * 8]); pb[p] += BK; }
    }
    const ushort_t* Ac = As[cur];
    const ushort_t* Bc = Bs[cur];
#pragma unroll
    for (int ks = 0; ks < KS; ks++) {
      bf16x8 af[NI], bf[NJ];
#pragma unroll
      for (int i = 0; i < NI; i++)
        af[i] = *(const bf16x8*)&Ac[(wm + i * 16 + ql) * BK + ((ks * 4 + qd) ^ sw) * 8];
#pragma unroll
      for (int j = 0; j < NJ; j++)
        bf[j] = *(const bf16x8*)&Bc[(wn + j * 16 + ql) * BK + ((ks * 4 + qd) ^ sw) * 8];
#pragma unroll
      for (int i = 0; i < NI; i++)
#pragma unroll
        for (int j = 0; j < NJ; j++)
          acc[i][j] = __builtin_amdgcn_mfma_f32_16x16x32_bf16(af[i], bf[j], acc[i][j], 0, 0, 0);
    }
    __syncthreads();  // readers of cur done + prefetch drained
    cur ^= 1;
  }

#pragma unroll
  for (int i = 0; i < NI; i++) {
    const int mr = m0 + wm + i * 16 + qd * 4;
#pragma unroll
    for (int j = 0; j < NJ; j++) {
      const int col = n0 + wn + j * 16 + ql;
      f32x4 v = acc[i][j];
      if constexpr (EPI == EPI_BF16) {
        const float bb = bias[col];
        ushort_t* o = (ushort_t*)outp;
#pragma unroll
        for (int r = 0; r < 4; r++) o[(size_t)(mr + r) * N + col] = f2bf((v[r] + bb) * oscale);
      } else if constexpr (EPI == EPI_QKV) {
        if (col < 1024) {  // Q half (pre-scaled by oscale for exp2 softmax)
          const float bb = bias[col];
          ushort_t* o = (ushort_t*)outp;
#pragma unroll
          for (int r = 0; r < 4; r++) o[(size_t)(mr + r) * 1024 + col] = f2bf((v[r] + bb) * oscale);
        } else if (col < 2048) {  // K -> [4096][1024] bf16
          const int c2 = col - 1024;
          const float bb = bias2[c2];
          ushort_t* o = (ushort_t*)outp2;
#pragma unroll
          for (int r = 0; r < 4; r++) o[(size_t)(mr + r) * 1024 + c2] = f2bf(v[r] + bb);
        } else {  // V -> V^T [B=2][H=16][HD=64][L=2048] bf16
          const int vc = col - 2048;
          const float bb = bias3[vc];
          const int h = vc >> 6, d = vc & 63;
          const int b = mr >> 11, l0 = mr & 2047;
          uint2 pk;
          pk.x = f2bf2(v[0] + bb, v[1] + bb);
          pk.y = f2bf2(v[2] + bb, v[3] + bb);
          *(uint2*)((ushort_t*)outp3 + ((((size_t)b * 16 + h) * 64 + d) * 2048 + l0)) = pk;
        }
      } else if constexpr (EPI == EPI_RESID) {
        const float bb = bias[col];
        float* o = (float*)outp;
#pragma unroll
        for (int r = 0; r < 4; r++) {
          size_t idx = (size_t)(mr + r) * N + col;
          o[idx] = resid[idx] + v[r] + bb;
        }
      } else if constexpr (EPI == EPI_GELU) {  // exact GELU, branchless fast erf
        const float bb = bias[col];
        ushort_t* o = (ushort_t*)outp;
#pragma unroll
        for (int r = 0; r < 4; r++)
          o[(size_t)(mr + r) * N + col] = f2bf(gelu_fast(v[r] + bb));
      }
    }
  }
}

// ---------------- 256x256 one-drain-per-tile GEMM (v2), BK=64, 8 waves, 128 KB LDS ----
template <int EPI>
__global__ __launch_bounds__(512, 2) void gemm256v2(
    const ushort_t* __restrict__ A, const ushort_t* __restrict__ Wb,
    const float* __restrict__ bias,
    void* __restrict__ outp, int M, int N, int K, float oscale) {
  __shared__ ushort_t As[2][256 * 64];
  __shared__ ushort_t Bs[2][256 * 64];
  const int t = threadIdx.x;
  const int w = t >> 6, lane = t & 63;
  const int qd = lane >> 4, ql = lane & 15;
  const int wr = w >> 2, wc = w & 3;  // 2(M) x 4(N) wave grid
  int bx = blockIdx.x, by = blockIdx.y;
  xcd_remap(gridDim.x, gridDim.y, bx, by);
  const int m0 = by * 256, n0 = bx * 256;
  const int sw = ql & 7;

  // staging pointers: gload p covers LDS rows [p*64, p*64+64) (512 thr x 16B = 64 rows)
  const ushort_t* pa[4];
  const ushort_t* pb[4];
#pragma unroll
  for (int p = 0; p < 4; p++) {
    const int n = p * 512 + t, row = n >> 3, c = (n & 7) ^ (row & 7);
    pa[p] = A + (size_t)(m0 + row) * K + c * 8;
    pb[p] = Wb + (size_t)(n0 + row) * K + c * 8;
  }

  // prologue: tile 0
#pragma unroll
  for (int p = 0; p < 4; p++) { gload_lds16(pa[p], &As[0][(p * 512 + t) * 8]); pa[p] += 64; }
#pragma unroll
  for (int p = 0; p < 4; p++) { gload_lds16(pb[p], &Bs[0][(p * 512 + t) * 8]); pb[p] += 64; }
  __syncthreads();

  f32x4 acc[8][4] = {};
  const int NT = K / 64;
  int cur = 0;

#define AFREAD(KS)                                                              \
  _Pragma("unroll") for (int i = 0; i < 8; i++)                                 \
      af[i] = *(const bf16x8*)&Ac[(wr * 128 + i * 16 + ql) * 64 +               \
                                  (((KS) * 4 + qd) ^ sw) * 8];
#define BFREAD(KS, NH)                                                          \
  _Pragma("unroll") for (int jj = 0; jj < 2; jj++)                              \
      bf[jj] = *(const bf16x8*)&Bc[(wc * 64 + (NH) * 32 + jj * 16 + ql) * 64 +  \
                                   (((KS) * 4 + qd) ^ sw) * 8];
#define MM(NH)                                                                  \
  __builtin_amdgcn_s_setprio(1);                                                \
  _Pragma("unroll") for (int i = 0; i < 8; i++)                                 \
      _Pragma("unroll") for (int jj = 0; jj < 2; jj++)                          \
          acc[i][(NH) * 2 + jj] = __builtin_amdgcn_mfma_f32_16x16x32_bf16(      \
              af[i], bf[jj], acc[i][(NH) * 2 + jj], 0, 0, 0);                   \
  __builtin_amdgcn_s_setprio(0);

  for (int T = 0; T < NT; ++T) {
    const ushort_t* Ac = As[cur];
    const ushort_t* Bc = Bs[cur];
    ushort_t* An = As[cur ^ 1];
    ushort_t* Bn = Bs[cur ^ 1];
    const bool st = (T + 1 < NT);
    bf16x8 af[8], bf[2];

    // phase 0 (ks0, nh0): stage ALL of tile T+1, read af(ks0)+bf, 16 MFMA
    if (st) {
#pragma unroll
      for (int p = 0; p < 4; p++) { gload_lds16(pa[p], &An[(p * 512 + t) * 8]); pa[p] += 64; }
#pragma unroll
      for (int p = 0; p < 4; p++) { gload_lds16(pb[p], &Bn[(p * 512 + t) * 8]); pb[p] += 64; }
    }
    AFREAD(0)
    BFREAD(0, 0)
    MM(0)
    __builtin_amdgcn_s_barrier();

    // phase 1 (ks0, nh1): af held
    BFREAD(0, 1)
    MM(1)
    __builtin_amdgcn_s_barrier();

    // phase 2 (ks1, nh0)
    AFREAD(1)
    BFREAD(1, 0)
    MM(0)
    __builtin_amdgcn_s_barrier();

    // phase 3 (ks1, nh1): tile-end drain + fenced barrier (buffer swap)
    BFREAD(1, 1)
    MM(1)
    if (st) asm volatile("s_waitcnt vmcnt(0)" ::: "memory");
    __builtin_amdgcn_sched_barrier(0);
    __builtin_amdgcn_s_barrier();
    __builtin_amdgcn_sched_barrier(0);
    cur ^= 1;
  }
#undef AFREAD
#undef BFREAD
#undef MM

#pragma unroll
  for (int i = 0; i < 8; i++) {
    const int mr = m0 + wr * 128 + i * 16 + qd * 4;
#pragma unroll
    for (int j = 0; j < 4; j++) {
      const int col = n0 + wc * 64 + j * 16 + ql;
      f32x4 v = acc[i][j];
      if constexpr (EPI == EPI_GELU) {
        const float bb = bias[col];
        ushort_t* o = (ushort_t*)outp;
#pragma unroll
        for (int r = 0; r < 4; r++)
          o[(size_t)(mr + r) * N + col] = f2bf(gelu_fast(v[r] + bb));
      } else if constexpr (EPI == EPI_BF16) {
        const float bb = bias[col];
        ushort_t* o = (ushort_t*)outp;
#pragma unroll
        for (int r = 0; r < 4; r++)
          o[(size_t)(mr + r) * N + col] = f2bf((v[r] + bb) * oscale);
      }
    }
  }
}

// ---------------- flash attention, softmax-1, deferred-softmax pipeline --------------
// QBLK=128, 4 waves, plain __syncthreads skeleton (verified primitives only).
// Iteration t: QK(t)->accNext [matrix pipe] runs CONCURRENTLY with SM(t-1)+PV(t-1)
// [VALU + matrix] from accPrev — QK(t) has no data-dep on SM(t-1), so VALU issues in
// MFMA shadows and period -> max(QK, SM+PV) instead of QK+SM+PV (R7 diagnosis).
// Buffers: K dbuf (iter t reads Ks[t%2], stages Ks[(t+1)%2]); V dbuf (iter t reads
// V(t-1) from Vs[(t-1)%2], stages V(t) into Vs[t%2]) — all write/read slots distinct
// within an iteration, and every staged buffer is drained by the iteration-ending
// __syncthreads (vmcnt(0)+lgkmcnt(0) semantics) before its reader next iteration.
// accA/accB: named double-buffer via 2x-unrolled loop + peeled iter 0 + epilogue.
__global__ __launch_bounds__(256, 2) void flash_attn(const ushort_t* __restrict__ Qg,
                                                     const ushort_t* __restrict__ Kg,
                                                     const ushort_t* __restrict__ VTg,
                                                     ushort_t* __restrict__ Og) {
  __shared__ ushort_t QPs[128 * 64];    // 16 KB: Q tile, then P (wave-private rows)
  __shared__ ushort_t Ks[2][64 * 64];   // 16 KB (dbuf K tile [l][d])
  __shared__ ushort_t Vs[2][64 * 64];   // 16 KB (dbuf V^T tile [d][l])
  const int t = threadIdx.x, w = t >> 6, lane = t & 63;
  const int qd = lane >> 4, ql = lane & 15;
  int bx = blockIdx.x, bh = blockIdx.y;
  xcd_remap(gridDim.x, gridDim.y, bx, bh);
  const int b = bh >> 4, h = bh & 15;
  const int n0 = bx * 128;
  const ushort_t* Qp = Qg + ((size_t)b * 2048 + n0) * 1024 + h * 64;
  const ushort_t* Kp = Kg + (size_t)b * 2048 * 1024 + h * 64;
  const ushort_t* Vp = VTg + (size_t)bh * 64 * 2048;
  const int sw = ql & 7;  // read-side swizzle key

  // hoisted staging pointers: K advances 64 rows, V 64 cols per stage
  const ushort_t* kp2[2];
  const ushort_t* vp2[2];
#pragma unroll
  for (int p = 0; p < 2; p++) {
    int n = p * 256 + t, row = n >> 3, c = (n & 7) ^ (row & 7);
    kp2[p] = Kp + (size_t)row * 1024 + c * 8;
    vp2[p] = Vp + (size_t)row * 2048 + c * 8;
  }

  // prologue: stage Q (swizzled) + K tile 0 only (V0 staged in iter 0)
#pragma unroll
  for (int p = 0; p < 4; p++) {
    int n = p * 256 + t, row = n >> 3, c = (n & 7) ^ (row & 7);
    gload_lds16(Qp + (size_t)row * 1024 + c * 8, &QPs[n * 8]);
  }
#pragma unroll
  for (int p = 0; p < 2; p++) { gload_lds16(kp2[p], &Ks[0][(p * 256 + t) * 8]); kp2[p] += 64 * 1024; }
  __syncthreads();

  // hoist Q fragments (loop-invariant); QPs becomes the P region afterwards
  bf16x8 aq[2][2];
#pragma unroll
  for (int i = 0; i < 2; i++)
#pragma unroll
    for (int ks = 0; ks < 2; ks++)
      aq[i][ks] = *(const bf16x8*)&QPs[(w * 32 + i * 16 + ql) * 64 + ((ks * 4 + qd) ^ sw) * 8];
  __syncthreads();  // all aq reads done before any wave writes P into QPs

  f32x4 accA[4][2], accB[4][2];
  f32x4 accO[2][4] = {};
  float lro2[2] = {0.f, 0.f};  // denom partials for n = w*32 + i*16 + ql (quad-partial)
  const f32x4 ZZ = {0.f, 0.f, 0.f, 0.f};

  // S^T = K.(Q*0.1803)^T into ACC (fresh accumulation, ZZ seed on ks=0)
#define QKSTEP(ACC, KSLOT)                                                                \
  { const ushort_t* Kc_ = &Ks[KSLOT][0];                                                  \
    bf16x8 bk[4];                                                                         \
    _Pragma("unroll") for (int j = 0; j < 4; j++)                                         \
      bk[j] = *(const bf16x8*)&Kc_[(j * 16 + ql) * 64 + ((0 + qd) ^ sw) * 8];             \
    __builtin_amdgcn_s_setprio(1);                                                        \
    _Pragma("unroll") for (int j = 0; j < 4; j++)                                         \
      _Pragma("unroll") for (int i = 0; i < 2; i++)                                       \
        ACC[j][i] = __builtin_amdgcn_mfma_f32_16x16x32_bf16(bk[j], aq[i][0], ZZ, 0, 0, 0);\
    __builtin_amdgcn_s_setprio(0);                                                        \
    _Pragma("unroll") for (int j = 0; j < 4; j++)                                         \
      bk[j] = *(const bf16x8*)&Kc_[(j * 16 + ql) * 64 + ((4 + qd) ^ sw) * 8];             \
    __builtin_amdgcn_s_setprio(1);                                                        \
    _Pragma("unroll") for (int j = 0; j < 4; j++)                                         \
      _Pragma("unroll") for (int i = 0; i < 2; i++)                                       \
        ACC[j][i] = __builtin_amdgcn_mfma_f32_16x16x32_bf16(bk[j], aq[i][1], ACC[j][i], 0, 0, 0); \
    __builtin_amdgcn_s_setprio(0);                                                        \
  }

  // p = exp2(s_hat); denom += p; pack 4 consecutive l -> one b64 P-write (wave-private)
#define SMSTEP(ACC)                                                                       \
  _Pragma("unroll") for (int j = 0; j < 4; j++)                                           \
    _Pragma("unroll") for (int i = 0; i < 2; i++) {                                       \
      f32x4 pp;                                                                           \
      _Pragma("unroll") for (int r = 0; r < 4; r++) {                                     \
        pp[r] = __builtin_amdgcn_exp2f(ACC[j][i][r]);                                     \
        lro2[i] += pp[r];                                                                 \
      }                                                                                   \
      const int nn = w * 32 + i * 16 + ql;                                                \
      const int coff = (((j * 2 + (qd >> 1)) ^ sw) << 3) + ((qd & 1) << 2);               \
      uint2 pk_; pk_.x = f2bf2(pp[0], pp[1]); pk_.y = f2bf2(pp[2], pp[3]);                \
      *(uint2*)&QPs[nn * 64 + coff] = pk_;                                                \
    }

  // O += P V (P rows intra-wave; V^T B-frags from Vs[VSLOT])
#define PVSTEP(VSLOT)                                                                     \
  { const ushort_t* Vc_ = &Vs[VSLOT][0];                                                  \
    _Pragma("unroll") for (int ks = 0; ks < 2; ks++) {                                    \
      bf16x8 ap[2], bv[4];                                                                \
      _Pragma("unroll") for (int i = 0; i < 2; i++)                                       \
        ap[i] = *(const bf16x8*)&QPs[(w * 32 + i * 16 + ql) * 64 + ((ks * 4 + qd) ^ sw) * 8]; \
      _Pragma("unroll") for (int jo = 0; jo < 4; jo++)                                    \
        bv[jo] = *(const bf16x8*)&Vc_[(jo * 16 + ql) * 64 + ((ks * 4 + qd) ^ sw) * 8];    \
      __builtin_amdgcn_s_setprio(1);                                                      \
      _Pragma("unroll") for (int i = 0; i < 2; i++)                                       \
        _Pragma("unroll") for (int jo = 0; jo < 4; jo++)                                  \
          accO[i][jo] = __builtin_amdgcn_mfma_f32_16x16x32_bf16(ap[i], bv[jo], accO[i][jo], 0, 0, 0); \
      __builtin_amdgcn_s_setprio(0);                                                      \
    }                                                                                     \
  }

#define STAGE_K(SLOT)                                                                     \
  _Pragma("unroll") for (int q_ = 0; q_ < 2; q_++) {                                      \
    gload_lds16(kp2[q_], &Ks[SLOT][(q_ * 256 + t) * 8]); kp2[q_] += 64 * 1024;            \
  }
#define STAGE_V(SLOT)                                                                     \
  _Pragma("unroll") for (int q_ = 0; q_ < 2; q_++) {                                      \
    gload_lds16(vp2[q_], &Vs[SLOT][(q_ * 256 + t) * 8]); vp2[q_] += 64;                   \
  }

  // iter 0 (peeled): stage K1->Ks[1], V0->Vs[0]; QK(0)->accA; no SM/PV yet
  STAGE_K(1)
  STAGE_V(0)
  QKSTEP(accA, 0)
  __syncthreads();

  for (int tt = 1; tt < 31; tt += 2) {
    // odd iter tt: read Ks[1]/Vs[0]; stage K(tt+1)->Ks[0], V(tt)->Vs[1]
    STAGE_K(0)
    STAGE_V(1)
    QKSTEP(accB, 1)
    SMSTEP(accA)
    PVSTEP(0)
    __syncthreads();
    // even iter tt+1: read Ks[0]/Vs[1]; stage K(tt+2)->Ks[1], V(tt+1)->Vs[0]
    STAGE_K(1)
    STAGE_V(0)
    QKSTEP(accA, 0)
    SMSTEP(accB)
    PVSTEP(1)
    __syncthreads();
  }
  // iter 31 (odd): read Ks[1]/Vs[0]; stage V(31)->Vs[1] only (no K32)
  STAGE_V(1)
  QKSTEP(accB, 1)
  SMSTEP(accA)
  PVSTEP(0)
  __syncthreads();
  // epilogue: SM(31) + PV(31) from Vs[1] (staged iter 31, drained by its barrier)
  SMSTEP(accB)
  PVSTEP(1)

#undef QKSTEP
#undef SMSTEP
#undef PVSTEP
#undef STAGE_K
#undef STAGE_V

  // finish denominators: sum across quads (each quad held disjoint l ranges)
  float dn[2];
#pragma unroll
  for (int i = 0; i < 2; i++) {
    float l = lro2[i];
    l += __shfl_xor(l, 16);
    l += __shfl_xor(l, 32);
    dn[i] = l + 1.0f;  // +1: implicit zero logit of softmax-1
  }

#pragma unroll
  for (int i = 0; i < 2; i++)
#pragma unroll
    for (int r = 0; r < 4; r++) {
      // denom for row n' = qd*4+r lives in lane ql = n' (quad-uniform after reduce)
      const float inv = 1.0f / __shfl(dn[i], qd * 4 + r);
      const int row = n0 + w * 32 + i * 16 + qd * 4 + r;
#pragma unroll
      for (int jo = 0; jo < 4; jo++)
        Og[((size_t)b * 2048 + row) * 1024 + h * 64 + jo * 16 + ql] =
            f2bf(accO[i][jo][r] * inv);
    }
}

// ---------------- launch ----------------
extern "C" void kernel_launch(void* const* d_in, const int* in_sizes, int n_in,
                              void* d_out, int out_size, void* d_ws, size_t ws_size,
                              hipStream_t stream) {
  const float* x_q = (const float*)d_in[0];
  const float* x_kv = (const float*)d_in[1];
  const float* qn_g = (const float*)d_in[2];
  const float* qn_b = (const float*)d_in[3];
  const float* kvn_g = (const float*)d_in[4];
  const float* kvn_b = (const float*)d_in[5];
  const float* Wq = (const float*)d_in[6];
  const float* bq = (const float*)d_in[7];
  const float* Wk = (const float*)d_in[8];
  const float* bk = (const float*)d_in[9];
  const float* Wv = (const float*)d_in[10];
  const float* bv = (const float*)d_in[11];
  const float* Wo = (const float*)d_in[12];
  const float* bo = (const float*)d_in[13];
  const float* n2_g = (const float*)d_in[14];
  const float* n2_b = (const float*)d_in[15];
  const float* W1 = (const float*)d_in[16];
  const float* b1 = (const float*)d_in[17];
  const float* W2 = (const float*)d_in[18];
  const float* b2 = (const float*)d_in[19];

  char* ws = (char*)d_ws;
  const size_t MB = 1ull << 20;
  ushort_t* WQKVB = (ushort_t*)(ws + 0 * MB);  // 6 MB ([Wq;Wk;Wv], 3072x1024)
  ushort_t* WoB = (ushort_t*)(ws + 6 * MB);    // 2 MB
  ushort_t* W1B = (ushort_t*)(ws + 8 * MB);    // 8 MB
  ushort_t* W2B = (ushort_t*)(ws + 16 * MB);   // 8 MB
  ushort_t* LNQ = (ushort_t*)(ws + 24 * MB);
  ushort_t* LNKV = (ushort_t*)(ws + 32 * MB);
  ushort_t* Qb = (ushort_t*)(ws + 40 * MB);
  ushort_t* Kb = (ushort_t*)(ws + 48 * MB);
  ushort_t* VTb = (ushort_t*)(ws + 56 * MB);
  ushort_t* AOb = (ushort_t*)(ws + 64 * MB);
  float* Xf = (float*)(ws + 72 * MB);          // 16 MB
  ushort_t* LN2 = (ushort_t*)(ws + 88 * MB);
  ushort_t* Hb = (ushort_t*)(ws + 24 * MB);    // 32 MB, overlays LNQ/LNKV/Qb/Kb (dead by MLP1)

  // fold softmax scale (1/8) and exp->exp2 (log2 e) into the Q projection
  const float QSCALE = 0.18033688011112042f;  // 0.125 * log2(e)

  // fused weight conversion + input LayerNorms (one launch, independent work)
  cvt_ln<<<20480, 256, 0, stream>>>(Wq, Wk, Wv, Wo, W1, W2, WQKVB, WoB, W1B, W2B,
                                    x_q, x_kv, qn_g, qn_b, kvn_g, kvn_b, LNQ, LNKV);

  // merged Q+K+V projection: N=3072, A = LNQ for n<1024 else LNKV (verified 128^2)
  gemm_bt<128, 128, 32, EPI_QKV><<<dim3(24, 32), 256, 0, stream>>>(
      LNQ, LNKV, WQKVB, bq, bk, bv, nullptr, Qb, Kb, VTb, 4096, 3072, 1024, QSCALE);

  // flash attention: deferred-softmax pipeline (plain __syncthreads skeleton)
  flash_attn<<<dim3(16, 32), 256, 0, stream>>>(Qb, Kb, VTb, AOb);

  // out-proj: BM=64 tiles -> 1024 blocks (4/CU); verified 2-dbuf structure
  gemm_bt<64, 64, 64, EPI_RESID><<<dim3(16, 64), 256, 0, stream>>>(
      AOb, nullptr, WoB, bo, nullptr, nullptr, x_q, Xf, nullptr, nullptr,
      4096, 1024, 1024, 1.0f);
  ln_bf16<<<4096, 256, 0, stream>>>(Xf, n2_g, n2_b, LN2);
  // MLP up-proj + GELU: 256^2 one-drain-per-tile kernel (grid 16x16 = 1 block/CU)
  gemm256v2<EPI_GELU><<<dim3(16, 16), 512, 0, stream>>>(
      LN2, W1B, b1, Hb, 4096, 4096, 1024, 1.0f);
  gemm_bt<64, 64, 64, EPI_RESID><<<dim3(16, 64), 256, 0, stream>>>(
      Hb, nullptr, W2B, b2, nullptr, nullptr, Xf, (float*)d_out, nullptr, nullptr,
      4096, 1024, 4096, 1.0f);
}